// Round 1
// 1047.887 us; speedup vs baseline: 1.2248x; 1.2248x over previous
//
#include <hip/hip_runtime.h>
#include <math.h>

#define SQ 1024  // S
#define EE 512   // E
#define NB 4     // B
#define NH 8     // H

typedef __attribute__((ext_vector_type(8))) short bfrag;       // 8 bf16 (4 VGPRs)
typedef __attribute__((ext_vector_type(4))) float f32x4;       // MFMA C/D
typedef __attribute__((ext_vector_type(4))) unsigned short u16x4;
typedef __attribute__((ext_vector_type(8))) unsigned short u16x8;

// Optimization barrier: forces materialization (rounding) so the compiler
// cannot FMA-contract or reassociate across numpy's op boundaries.
__device__ __forceinline__ float sep(float x) {
  asm volatile("" : "+v"(x));
  return x;
}

__device__ __forceinline__ unsigned short f2bf(float f) {
  unsigned u = __builtin_bit_cast(unsigned, f);
  unsigned r = (u + 0x7fffu + ((u >> 16) & 1u)) >> 16;
  return (unsigned short)r;
}
__device__ __forceinline__ float bf2f(unsigned short h) {
  unsigned u = ((unsigned)h) << 16;
  return __builtin_bit_cast(float, u);
}

__device__ __forceinline__ void split4(float4 v, u16x4& h, u16x4& l) {
  h.x = f2bf(v.x); l.x = f2bf(v.x - bf2f(h.x));
  h.y = f2bf(v.y); l.y = f2bf(v.y - bf2f(h.y));
  h.z = f2bf(v.z); l.z = f2bf(v.z - bf2f(h.z));
  h.w = f2bf(v.w); l.w = f2bf(v.w - bf2f(h.w));
}

// ================= LayerNorm, numpy-exact fp32 (np.mean pairwise) — FROZEN =================
__global__ __launch_bounds__(64) void ln_np(const float* __restrict__ x,
                                            const float* __restrict__ g,
                                            const float* __restrict__ b,
                                            float* __restrict__ y) {
  __shared__ float xs[EE];
  __shared__ float bc[2];
  long long t = blockIdx.x;
  int lane = threadIdx.x;
#pragma unroll
  for (int m = 0; m < 8; m++) xs[lane + 64 * m] = x[t * EE + lane + 64 * m];
  __syncthreads();
  int l = lane >> 3, a = lane & 7;
  float r = 0.f;
  if (lane < 32) {
    r = xs[l * 128 + a];
#pragma unroll
    for (int m = 1; m < 16; m++) r = r + xs[l * 128 + 8 * m + a];
  }
  r = r + __shfl_xor(r, 1);
  r = r + __shfl_xor(r, 2);
  r = r + __shfl_xor(r, 4);
  r = r + __shfl_xor(r, 8);
  r = r + __shfl_xor(r, 16);
  if (lane == 0) bc[0] = r / 512.0f;
  __syncthreads();
  float mean = bc[0];
  r = 0.f;
  if (lane < 32) {
#pragma unroll
    for (int m = 0; m < 16; m++) {
      float d = sep(xs[l * 128 + 8 * m + a] - mean);
      float s2 = sep(d * d);
      r = (m == 0) ? s2 : (r + s2);
    }
  }
  r = r + __shfl_xor(r, 1);
  r = r + __shfl_xor(r, 2);
  r = r + __shfl_xor(r, 4);
  r = r + __shfl_xor(r, 8);
  r = r + __shfl_xor(r, 16);
  if (lane == 0) bc[1] = r / 512.0f;
  __syncthreads();
  float var = bc[1];
  float rs = 1.0f / sqrtf(var + 1e-5f);
#pragma unroll
  for (int m = 0; m < 8; m++) {
    int i = lane + 64 * m;
    float d = sep(xs[i] - mean);
    float t1 = sep(d * rs);
    float t2 = sep(t1 * g[i]);
    y[t * EE + i] = t2 + b[i];
  }
}

// ================= distances — FROZEN math; s-range split over blockIdx.y =================
__global__ __launch_bounds__(256) void dist_np(const float* __restrict__ nq,
                                               const float* __restrict__ conv_w,
                                               const float* __restrict__ conv_b,
                                               float* __restrict__ dist) {
  int bh = blockIdx.x;
  int b = bh >> 3, h = bh & 7;
  float cb = conv_b[h];
  const float* W = conv_w + (long long)h * EE * 3;
  int s = blockIdx.y * 256 + threadIdx.x;
  float d = cb;
#pragma unroll
  for (int k = 0; k < 3; k++) {
    int t = s - 2 + k;
    if (t < 0) continue;
    const float* row = nq + ((long long)b * SQ + t) * EE;
    float acc = 0.f;
    for (int e = 0; e < EE; e++) acc = __builtin_fmaf(row[e], W[e * 3 + k], acc);
    d = sep(d + acc);
  }
  dist[(long long)bh * SQ + s] = (float)tanh((double)d);
}

// ================= fp32 tiled NT-GEMM — FROZEN DAG (R12, byte-identical) =================
__device__ __forceinline__ float gelu_exact(float x) {
  return 0.5f * x * (1.f + erff(x / 1.41421356237309504880f));
}

template <int ACT, int SPLITK>
__global__ __launch_bounds__(256) void gemm_nt(const float* __restrict__ A, int lda, long long sA,
                                               const float* __restrict__ B, int ldb, long long sB,
                                               const float* __restrict__ bias,
                                               const float* __restrict__ Res,
                                               float* __restrict__ C, int ldc, long long sC,
                                               int K, float alpha) {
  __shared__ float As[16][68];
  __shared__ float Bs[16][68];
  int z = blockIdx.z;
  A += (long long)z * sA;
  B += (long long)z * sB;
  C += (long long)z * sC;
  int m0 = blockIdx.y * 64, n0 = blockIdx.x * 64;
  int tid = threadIdx.x;
  int lr = tid >> 2, lc = tid & 3;
  int tx = tid & 15, ty = tid >> 4;
  float acc[4][4] = {};
  float acc2[4][4] = {};
  const float* Arow = A + (long long)(m0 + lr) * lda + lc * 4;
  const float* Brow = B + (long long)(n0 + lr) * ldb + lc * 4;
  float4 a4 = *(const float4*)(Arow);
  float4 b4 = *(const float4*)(Brow);
  for (int k0 = 0; k0 < K; k0 += 16) {
    __syncthreads();
    As[lc * 4 + 0][lr] = a4.x; As[lc * 4 + 1][lr] = a4.y;
    As[lc * 4 + 2][lr] = a4.z; As[lc * 4 + 3][lr] = a4.w;
    Bs[lc * 4 + 0][lr] = b4.x; Bs[lc * 4 + 1][lr] = b4.y;
    Bs[lc * 4 + 2][lr] = b4.z; Bs[lc * 4 + 3][lr] = b4.w;
    __syncthreads();
    int kn = (k0 + 16 < K) ? (k0 + 16) : k0;
    float4 a4n = *(const float4*)(Arow + kn);
    float4 b4n = *(const float4*)(Brow + kn);
    float(*tgt)[4] = (SPLITK > 0 && k0 >= SPLITK) ? acc2 : acc;
#pragma unroll
    for (int kk = 0; kk < 16; kk++) {
      float4 av = *(const float4*)&As[kk][ty * 4];
      float4 bv = *(const float4*)&Bs[kk][tx * 4];
      float a[4] = {av.x, av.y, av.z, av.w};
      float bb[4] = {bv.x, bv.y, bv.z, bv.w};
#pragma unroll
      for (int i = 0; i < 4; i++)
#pragma unroll
        for (int j = 0; j < 4; j++) tgt[i][j] += a[i] * bb[j];
    }
    a4 = a4n;
    b4 = b4n;
  }
  if (SPLITK > 0) {
#pragma unroll
    for (int i = 0; i < 4; i++)
#pragma unroll
      for (int j = 0; j < 4; j++) acc[i][j] = sep(acc[i][j]) + acc2[i][j];
  }
  float4 bias4 = make_float4(0.f, 0.f, 0.f, 0.f);
  if (ACT != 2 && bias) bias4 = *(const float4*)(bias + n0 + tx * 4);
#pragma unroll
  for (int i = 0; i < 4; i++) {
    int row = m0 + ty * 4 + i;
    float o[4];
    if (ACT == 2) {
#pragma unroll
      for (int j = 0; j < 4; j++) o[j] = acc[i][j] / alpha;
    } else {
      o[0] = sep(acc[i][0] * alpha) + bias4.x;
      o[1] = sep(acc[i][1] * alpha) + bias4.y;
      o[2] = sep(acc[i][2] * alpha) + bias4.z;
      o[3] = sep(acc[i][3] * alpha) + bias4.w;
    }
    if (ACT == 1) {
#pragma unroll
      for (int j = 0; j < 4; j++) o[j] = gelu_exact(o[j]);
    }
    if (Res) {
      float4 r4 = *(const float4*)(Res + (long long)row * ldc + n0 + tx * 4);
      o[0] = sep(o[0]) + r4.x; o[1] = sep(o[1]) + r4.y;
      o[2] = sep(o[2]) + r4.z; o[3] = sep(o[3]) + r4.w;
    }
    *(float4*)(C + (long long)row * ldc + n0 + tx * 4) = make_float4(o[0], o[1], o[2], o[3]);
  }
}

// ================= gated row sums: np.sum pairwise(1024) — FROZEN =================
__global__ __launch_bounds__(64) void rowsum_np(const float* __restrict__ scores,
                                                const float* __restrict__ dist,
                                                float* __restrict__ invrs) {
  __shared__ float wsm[SQ];
  int i = blockIdx.x;
  int z = blockIdx.y;
  int b = z >> 3;
  const float* srow = scores + ((long long)b * SQ + i) * SQ;
  const float* dz = dist + (long long)z * SQ;
  float di = dz[i];
  int lane = threadIdx.x;
#pragma unroll
  for (int m = 0; m < 16; m++) {
    int j = lane + 64 * m;
    float e = (float)exp((double)(dz[j] - di));
    float gg = 1.f / (1.f + e);
    wsm[j] = srow[j] * gg;
  }
  __syncthreads();
  int l = lane >> 3, a = lane & 7;
  float r = wsm[l * 128 + a];
#pragma unroll
  for (int m = 1; m < 16; m++) r = r + wsm[l * 128 + 8 * m + a];
  r = r + __shfl_xor(r, 1);
  r = r + __shfl_xor(r, 2);
  r = r + __shfl_xor(r, 4);
  r = r + __shfl_xor(r, 8);
  r = r + __shfl_xor(r, 16);
  r = r + __shfl_xor(r, 32);
  if (lane == 0) invrs[(long long)z * SQ + i] = 1.f / (r + 1e-12f);
}

// ================= ctx GEMM wide-N (nc=4) — fp32 FALLBACK (kept for rollback) =================
__global__ __launch_bounds__(256) void ctx_gemm_w(const float* __restrict__ scores,
                                                  const float* __restrict__ dist,
                                                  const float* __restrict__ invrs,
                                                  const float* __restrict__ qkv,
                                                  float* __restrict__ ctx) {
  __shared__ float As[16][68];
  __shared__ float Bs[16][264];
  int z = blockIdx.z, b = z >> 3, h = z & 7;
  const float* A = scores + (long long)b * SQ * SQ;
  const float* V = qkv + (long long)b * SQ * (3 * EE) + 2 * EE;
  float* C = ctx + (long long)b * SQ * (NH * EE) + h * EE;
  const float* dz = dist + (long long)z * SQ;
  int m0 = blockIdx.y * 64;
  int n0 = blockIdx.x * 256;
  int tid = threadIdx.x;
  int lr = tid >> 2, lc = tid & 3;
  int bk = tid >> 4, bc = tid & 15;
  int tx = tid & 15, ty = tid >> 4;
  int arow = m0 + lr;
  float di = dz[arow];
  float inv = invrs[(long long)z * SQ + arow];
  float acc[4][4][4] = {};
  const float* Srow = A + (long long)arow * SQ + lc * 4;
  const float* Vbase = V + (long long)bk * (3 * EE) + n0 + bc * 4;
  float4 s4 = *(const float4*)(Srow);
  float4 d4 = *(const float4*)(dz + lc * 4);
  float4 v4[4];
#pragma unroll
  for (int nc = 0; nc < 4; nc++) v4[nc] = *(const float4*)(Vbase + nc * 64);
  for (int k0 = 0; k0 < SQ; k0 += 16) {
    __syncthreads();
    float g0 = 1.f / (1.f + expf(d4.x - di));
    float g1 = 1.f / (1.f + expf(d4.y - di));
    float g2 = 1.f / (1.f + expf(d4.z - di));
    float g3 = 1.f / (1.f + expf(d4.w - di));
    As[lc * 4 + 0][lr] = (s4.x * g0) * inv;
    As[lc * 4 + 1][lr] = (s4.y * g1) * inv;
    As[lc * 4 + 2][lr] = (s4.z * g2) * inv;
    As[lc * 4 + 3][lr] = (s4.w * g3) * inv;
#pragma unroll
    for (int nc = 0; nc < 4; nc++)
      *(float4*)&Bs[bk][nc * 64 + bc * 4] = v4[nc];
    __syncthreads();
    int kn = (k0 + 16 < SQ) ? (k0 + 16) : k0;
    float4 s4n = *(const float4*)(Srow + kn);
    float4 d4n = *(const float4*)(dz + kn + lc * 4);
    float4 v4n[4];
#pragma unroll
    for (int nc = 0; nc < 4; nc++)
      v4n[nc] = *(const float4*)(Vbase + (long long)kn * (3 * EE) + nc * 64);
#pragma unroll
    for (int kk = 0; kk < 16; kk++) {
      float4 av = *(const float4*)&As[kk][ty * 4];
      float a[4] = {av.x, av.y, av.z, av.w};
#pragma unroll
      for (int nc = 0; nc < 4; nc++) {
        float4 bv = *(const float4*)&Bs[kk][nc * 64 + tx * 4];
        float bb[4] = {bv.x, bv.y, bv.z, bv.w};
#pragma unroll
        for (int i = 0; i < 4; i++)
#pragma unroll
          for (int j = 0; j < 4; j++) acc[nc][i][j] += a[i] * bb[j];
      }
    }
    s4 = s4n;
    d4 = d4n;
#pragma unroll
    for (int nc = 0; nc < 4; nc++) v4[nc] = v4n[nc];
  }
#pragma unroll
  for (int i = 0; i < 4; i++) {
    int row = m0 + ty * 4 + i;
#pragma unroll
    for (int nc = 0; nc < 4; nc++) {
      *(float4*)(C + (long long)row * (NH * EE) + n0 + nc * 64 + tx * 4) =
          make_float4(acc[nc][i][0], acc[nc][i][1], acc[nc][i][2], acc[nc][i][3]);
    }
  }
}

// ================= V transpose + bf16 hi/lo split:  VhT/VlT[b][e][j] = split(V[b][j][e]) =================
__global__ __launch_bounds__(256) void vsplit_t(const float* __restrict__ qkv,
                                                unsigned short* __restrict__ VhT,
                                                unsigned short* __restrict__ VlT) {
  __shared__ float tile[64][65];
  int b = blockIdx.z;
  int j0 = blockIdx.x * 64;  // S tile
  int e0 = blockIdx.y * 64;  // E tile
  const float* V = qkv + (long long)b * SQ * (3 * EE) + 2 * EE;
  unsigned short* Vh = VhT + (long long)b * EE * SQ;
  unsigned short* Vl = VlT + (long long)b * EE * SQ;
  int tx = threadIdx.x & 15, ty = threadIdx.x >> 4;
#pragma unroll
  for (int r = 0; r < 4; r++) {
    int j = j0 + ty + r * 16;
    float4 v = *(const float4*)(V + (long long)j * (3 * EE) + e0 + tx * 4);
    tile[ty + r * 16][tx * 4 + 0] = v.x;
    tile[ty + r * 16][tx * 4 + 1] = v.y;
    tile[ty + r * 16][tx * 4 + 2] = v.z;
    tile[ty + r * 16][tx * 4 + 3] = v.w;
  }
  __syncthreads();
#pragma unroll
  for (int r = 0; r < 4; r++) {
    int el = ty + r * 16;
    float4 f;
    f.x = tile[tx * 4 + 0][el];
    f.y = tile[tx * 4 + 1][el];
    f.z = tile[tx * 4 + 2][el];
    f.w = tile[tx * 4 + 3][el];
    u16x4 hh, ll;
    split4(f, hh, ll);
    long long o = (long long)(e0 + el) * SQ + j0 + tx * 4;
    *(u16x4*)(Vh + o) = hh;
    *(u16x4*)(Vl + o) = ll;
  }
}

// ================= ctx GEMM via bf16x3 MFMA (numerator-side, frozen scores/dist/invrs inputs) =================
// ctx[b,h,i,e] = sum_j ((scores[i,j]*sigmoid(di-dj))*inv_i) * V[j,e]
// A computed on the fly in fp32 (identical expression to ctx_gemm_w), split hi/lo bf16.
// B pre-split/pre-transposed by vsplit_t. Tile 64x128, 4 waves, K-step 32, mfma 16x16x32.
__global__ __launch_bounds__(256) void ctx_bf3(const float* __restrict__ scores,
                                               const float* __restrict__ dist,
                                               const float* __restrict__ invrs,
                                               const unsigned short* __restrict__ VhT,
                                               const unsigned short* __restrict__ VlT,
                                               float* __restrict__ ctx) {
  constexpr int BN = 128;
  constexpr int NF = BN / 64;  // 2 n-frags per wave
  __shared__ __align__(16) unsigned short Ah[64][40], Al[64][40];
  __shared__ __align__(16) unsigned short Bh[BN][40], Bl[BN][40];
  int z = blockIdx.z, b = z >> 3, h = z & 7;
  const float* Sb = scores + (long long)b * SQ * SQ;
  const unsigned short* Vh = VhT + (long long)b * EE * SQ;
  const unsigned short* Vl = VlT + (long long)b * EE * SQ;
  float* C = ctx + (long long)b * SQ * (NH * EE) + h * EE;
  const float* dz = dist + (long long)z * SQ;
  int m0 = blockIdx.y * 64, n0 = blockIdx.x * BN;
  int tid = threadIdx.x;
  int wave = tid >> 6, lane = tid & 63;
  int quad = lane >> 4, l16 = lane & 15;
  int colb0 = wave * (BN / 4);
  f32x4 acc[4][NF];
#pragma unroll
  for (int mf = 0; mf < 4; mf++)
#pragma unroll
    for (int nf = 0; nf < NF; nf++) acc[mf][nf] = (f32x4)(0.f);

  // A staging: row aam, k-chunks (aakc + r*4)*4, r=0..1  -> 8 floats/thread/K-step
  int aam = tid & 63, aakc = tid >> 6;
  float di = dz[m0 + aam];
  float inv = invrs[(long long)z * SQ + m0 + aam];
  const float* Srow = Sb + (long long)(m0 + aam) * SQ;
  // B staging: row bbn (= output col e), u16x8 chunks at bbk*16 + r*8, r=0..1
  int bbn = tid & (BN - 1);
  int bbk = tid / BN;  // 0..1
  const unsigned short* VhRow = Vh + (long long)(n0 + bbn) * SQ + bbk * 16;
  const unsigned short* VlRow = Vl + (long long)(n0 + bbn) * SQ + bbk * 16;

  u16x4 aH[2], aL[2];
  u16x8 bH[2], bL[2];

  auto loadconv = [&](int kb) {
#pragma unroll
    for (int r = 0; r < 2; r++) {
      int kc = aakc + r * 4;
      float4 s4 = *(const float4*)(Srow + kb + kc * 4);
      float4 d4 = *(const float4*)(dz + kb + kc * 4);
      float4 a;
      a.x = (s4.x * (1.f / (1.f + expf(d4.x - di)))) * inv;
      a.y = (s4.y * (1.f / (1.f + expf(d4.y - di)))) * inv;
      a.z = (s4.z * (1.f / (1.f + expf(d4.z - di)))) * inv;
      a.w = (s4.w * (1.f / (1.f + expf(d4.w - di)))) * inv;
      split4(a, aH[r], aL[r]);
      bH[r] = *(const u16x8*)(VhRow + kb + r * 8);
      bL[r] = *(const u16x8*)(VlRow + kb + r * 8);
    }
  };

  loadconv(0);
  for (int k0 = 0; k0 < SQ; k0 += 32) {
    __syncthreads();
#pragma unroll
    for (int r = 0; r < 2; r++) {
      *(u16x4*)&Ah[aam][(aakc + r * 4) * 4] = aH[r];
      *(u16x4*)&Al[aam][(aakc + r * 4) * 4] = aL[r];
      *(u16x8*)&Bh[bbn][bbk * 16 + r * 8] = bH[r];
      *(u16x8*)&Bl[bbn][bbk * 16 + r * 8] = bL[r];
    }
    __syncthreads();
    int kn = (k0 + 32 < SQ) ? (k0 + 32) : k0;  // clamped dummy reload
    loadconv(kn);
    bfrag bhf[NF], blf[NF];
#pragma unroll
    for (int nf = 0; nf < NF; nf++) {
      bhf[nf] = *(const bfrag*)&Bh[colb0 + nf * 16 + l16][quad * 8];
      blf[nf] = *(const bfrag*)&Bl[colb0 + nf * 16 + l16][quad * 8];
    }
#pragma unroll
    for (int mf = 0; mf < 4; mf++) {
      bfrag ah = *(const bfrag*)&Ah[mf * 16 + l16][quad * 8];
      bfrag al = *(const bfrag*)&Al[mf * 16 + l16][quad * 8];
#pragma unroll
      for (int nf = 0; nf < NF; nf++) {
        acc[mf][nf] = __builtin_amdgcn_mfma_f32_16x16x32_bf16(al, bhf[nf], acc[mf][nf], 0, 0, 0);
        acc[mf][nf] = __builtin_amdgcn_mfma_f32_16x16x32_bf16(ah, blf[nf], acc[mf][nf], 0, 0, 0);
        acc[mf][nf] = __builtin_amdgcn_mfma_f32_16x16x32_bf16(ah, bhf[nf], acc[mf][nf], 0, 0, 0);
      }
    }
  }
  // epilogue: C/D layout row = quad*4 + r, col = l16
#pragma unroll
  for (int mf = 0; mf < 4; mf++) {
#pragma unroll
    for (int nf = 0; nf < NF; nf++) {
      int col = n0 + colb0 + nf * 16 + l16;
#pragma unroll
      for (int r = 0; r < 4; r++) {
        int row = m0 + mf * 16 + quad * 4 + r;
        C[(long long)row * (NH * EE) + col] = acc[mf][nf][r];
      }
    }
  }
}

// ================= bf16x3 MFMA NT-GEMM (numerator-side only) =================
// C = act(A@B^T + bias) (+Res). fp32 split into hi/lo bf16; 3 MFMA terms per
// product (rel err ~2^-17). Tile 64 x BN, 4 waves, K-step 32, mfma 16x16x32.
template <int ACT, int BN>
__global__ __launch_bounds__(256) void gemm_bf3(const float* __restrict__ A, int lda,
                                                const float* __restrict__ B, int ldb,
                                                const float* __restrict__ bias,
                                                const float* __restrict__ Res,
                                                float* __restrict__ C, int ldc, int K) {
  constexpr int NF = BN / 64;        // n-frags per wave (16 cols each)
  constexpr int NREPB = BN / 32;     // B staging reps (float4 per thread)
  __shared__ __align__(16) unsigned short Ah[64][40], Al[64][40];
  __shared__ __align__(16) unsigned short Bh[BN][40], Bl[BN][40];
  int m0 = blockIdx.y * 64, n0 = blockIdx.x * BN;
  int tid = threadIdx.x;
  int wave = tid >> 6, lane = tid & 63;
  int quad = lane >> 4, l16 = lane & 15;
  int colb0 = wave * (BN / 4);
  f32x4 acc[4][NF];
#pragma unroll
  for (int mf = 0; mf < 4; mf++)
#pragma unroll
    for (int nf = 0; nf < NF; nf++) acc[mf][nf] = (f32x4)(0.f);

  int aam = tid & 63, aakc = tid >> 6;            // +r*4 on kc per rep
  float4 aldg[2], bldg[NREPB];
#pragma unroll
  for (int r = 0; r < 2; r++)
    aldg[r] = *(const float4*)(A + (long long)(m0 + aam) * lda + (aakc + r * 4) * 4);
  int bbn = tid & (BN - 1), bbkc = tid / BN;
#pragma unroll
  for (int r = 0; r < NREPB; r++)
    bldg[r] = *(const float4*)(B + (long long)(n0 + bbn) * ldb + (bbkc + r * (256 / BN)) * 4);

  for (int k0 = 0; k0 < K; k0 += 32) {
    __syncthreads();
#pragma unroll
    for (int r = 0; r < 2; r++) {
      float4 v = aldg[r];
      int kc = aakc + r * 4;
      u16x4 h, l;
      h.x = f2bf(v.x); l.x = f2bf(v.x - bf2f(h.x));
      h.y = f2bf(v.y); l.y = f2bf(v.y - bf2f(h.y));
      h.z = f2bf(v.z); l.z = f2bf(v.z - bf2f(h.z));
      h.w = f2bf(v.w); l.w = f2bf(v.w - bf2f(h.w));
      *(u16x4*)&Ah[aam][kc * 4] = h;
      *(u16x4*)&Al[aam][kc * 4] = l;
    }
#pragma unroll
    for (int r = 0; r < NREPB; r++) {
      float4 v = bldg[r];
      int kc = bbkc + r * (256 / BN);
      u16x4 h, l;
      h.x = f2bf(v.x); l.x = f2bf(v.x - bf2f(h.x));
      h.y = f2bf(v.y); l.y = f2bf(v.y - bf2f(h.y));
      h.z = f2bf(v.z); l.z = f2bf(v.z - bf2f(h.z));
      h.w = f2bf(v.w); l.w = f2bf(v.w - bf2f(h.w));
      *(u16x4*)&Bh[bbn][kc * 4] = h;
      *(u16x4*)&Bl[bbn][kc * 4] = l;
    }
    __syncthreads();
    int kn = (k0 + 32 < K) ? (k0 + 32) : k0;  // clamped dummy reload
#pragma unroll
    for (int r = 0; r < 2; r++)
      aldg[r] = *(const float4*)(A + (long long)(m0 + aam) * lda + kn + (aakc + r * 4) * 4);
#pragma unroll
    for (int r = 0; r < NREPB; r++)
      bldg[r] = *(const float4*)(B + (long long)(n0 + bbn) * ldb + kn + (bbkc + r * (256 / BN)) * 4);
    bfrag bh[NF], bl[NF];
#pragma unroll
    for (int nf = 0; nf < NF; nf++) {
      bh[nf] = *(const bfrag*)&Bh[colb0 + nf * 16 + l16][quad * 8];
      bl[nf] = *(const bfrag*)&Bl[colb0 + nf * 16 + l16][quad * 8];
    }
#pragma unroll
    for (int mf = 0; mf < 4; mf++) {
      bfrag ah = *(const bfrag*)&Ah[mf * 16 + l16][quad * 8];
      bfrag al = *(const bfrag*)&Al[mf * 16 + l16][quad * 8];
#pragma unroll
      for (int nf = 0; nf < NF; nf++) {
        acc[mf][nf] = __builtin_amdgcn_mfma_f32_16x16x32_bf16(al, bh[nf], acc[mf][nf], 0, 0, 0);
        acc[mf][nf] = __builtin_amdgcn_mfma_f32_16x16x32_bf16(ah, bl[nf], acc[mf][nf], 0, 0, 0);
        acc[mf][nf] = __builtin_amdgcn_mfma_f32_16x16x32_bf16(ah, bh[nf], acc[mf][nf], 0, 0, 0);
      }
    }
  }
  // epilogue: C/D layout row = quad*4 + r, col = lane&15
#pragma unroll
  for (int mf = 0; mf < 4; mf++) {
#pragma unroll
    for (int nf = 0; nf < NF; nf++) {
      int col = n0 + colb0 + nf * 16 + l16;
      float bi = bias ? bias[col] : 0.f;
#pragma unroll
      for (int r = 0; r < 4; r++) {
        int row = m0 + mf * 16 + quad * 4 + r;
        float o = acc[mf][nf][r] + bi;
        if (ACT == 1) o = gelu_exact(o);
        if (Res) o = o + Res[(long long)row * ldc + col];
        C[(long long)row * ldc + col] = o;
      }
    }
  }
}

extern "C" void kernel_launch(void* const* d_in, const int* in_sizes, int n_in,
                              void* d_out, int out_size, void* d_ws, size_t ws_size,
                              hipStream_t stream) {
  const float* query     = (const float*)d_in[0];
  const float* ln1_g     = (const float*)d_in[1];
  const float* ln1_b     = (const float*)d_in[2];
  const float* in_proj_w = (const float*)d_in[3];
  const float* in_proj_b = (const float*)d_in[4];
  const float* out_w     = (const float*)d_in[5];
  const float* out_b     = (const float*)d_in[6];
  const float* conv_w    = (const float*)d_in[7];
  const float* conv_b    = (const float*)d_in[8];
  const float* ln2_g     = (const float*)d_in[9];
  const float* ln2_b     = (const float*)d_in[10];
  const float* mlp_w1    = (const float*)d_in[11];
  const float* mlp_b1    = (const float*)d_in[12];
  const float* mlp_w2    = (const float*)d_in[13];
  const float* mlp_b2    = (const float*)d_in[14];
  float* out = (float*)d_out;
  char* ws = (char*)d_ws;

  // R7-exact layout: peak 112.25 MiB (proven safe)
  float* nq     = (float*)(ws + 0);                      // 8 MiB
  float* qkv    = (float*)(ws + (8ull << 20));           // 24 MiB
  float* dist   = (float*)(ws + (32ull << 20));          // 128 KiB
  float* invrs  = (float*)(ws + (32ull << 20) + 131072); // 128 KiB
  float* scores = (float*)(ws + (32ull << 20) + 262144); // 16 MiB
  float* ctx    = (float*)(ws + (48ull << 20) + 262144); // 64 MiB -> 112.25 MiB
  float* ln2out = scores;                                // reuse
  float* hbuf   = nq;                                    // reuse nq+qkv (32 MiB)
  // VhT/VlT live in the dead nq region (nq unused between qkv-GEMM and MLP1's hbuf reuse):
  unsigned short* VhT = (unsigned short*)(ws + 0);             // 4 MiB
  unsigned short* VlT = (unsigned short*)(ws + (4ull << 20));  // 4 MiB (exactly fills nq's 8 MiB)

  // 1. LN1 (frozen)
  ln_np<<<dim3(NB * SQ), 64, 0, stream>>>(query, ln1_g, ln1_b, nq);
  // 2. distances (frozen)
  dist_np<<<dim3(NB * NH, 4), 256, 0, stream>>>(nq, conv_w, conv_b, dist);
  // 3. qkv (frozen chain)  M=4096 N=1536 K=512
  gemm_nt<0, 384><<<dim3(24, 64, 1), 256, 0, stream>>>(nq, EE, 0, in_proj_w, EE, 0,
                                                       in_proj_b, nullptr, qkv, 3 * EE, 0, EE, 1.f);
  // 3b. V transpose + bf16 hi/lo split (nq is dead from here until step 9)
  vsplit_t<<<dim3(16, 8, NB), 256, 0, stream>>>(qkv, VhT, VlT);
  // 4. scores (frozen chain + true division)  M=N=1024 K=512, batched B
  gemm_nt<2, 384><<<dim3(16, 16, NB), 256, 0, stream>>>(
      qkv, 3 * EE, (long long)SQ * 3 * EE, qkv + EE, 3 * EE, (long long)SQ * 3 * EE,
      nullptr, nullptr, scores, SQ, (long long)SQ * SQ, EE, sqrtf(512.0f));
  // 5. gated row sums (frozen)
  rowsum_np<<<dim3(SQ, NB * NH), 64, 0, stream>>>(scores, dist, invrs);
  // 6. ctx via bf16x3 MFMA  M=1024 N=512 K=1024, z = B*H
  ctx_bf3<<<dim3(EE / 128, 16, NB * NH), 256, 0, stream>>>(scores, dist, invrs, VhT, VlT, ctx);
  // 7. attn_out + residual (MFMA bf16x3)  M=4096 N=512 K=4096
  gemm_bf3<0, 64><<<dim3(8, 64), 256, 0, stream>>>(ctx, NH * EE, out_w, NH * EE,
                                                   out_b, query, out, EE, NH * EE);
  // 8. LN2
  ln_np<<<dim3(NB * SQ), 64, 0, stream>>>(out, ln2_g, ln2_b, ln2out);
  // 9. MLP1 + gelu (MFMA bf16x3)  M=4096 N=2048 K=512
  gemm_bf3<1, 128><<<dim3(16, 64), 256, 0, stream>>>(ln2out, EE, mlp_w1, EE,
                                                     mlp_b1, nullptr, hbuf, 4 * EE, EE);
  // 10. MLP2 + residual (MFMA bf16x3)  M=4096 N=512 K=2048
  gemm_bf3<0, 64><<<dim3(8, 64), 256, 0, stream>>>(hbuf, 4 * EE, mlp_w2, 4 * EE,
                                                   mlp_b2, out, out, EE, 4 * EE);
}

// Round 2
// 992.105 us; speedup vs baseline: 1.2937x; 1.0562x over previous
//
#include <hip/hip_runtime.h>
#include <math.h>

#define SQ 1024  // S
#define EE 512   // E
#define NB 4     // B
#define NH 8     // H

typedef __attribute__((ext_vector_type(8))) short bfrag;       // 8 bf16 (4 VGPRs)
typedef __attribute__((ext_vector_type(4))) float f32x4;       // MFMA C/D
typedef __attribute__((ext_vector_type(4))) unsigned short u16x4;
typedef __attribute__((ext_vector_type(8))) unsigned short u16x8;

// Optimization barrier: forces materialization (rounding) so the compiler
// cannot FMA-contract or reassociate across numpy's op boundaries.
__device__ __forceinline__ float sep(float x) {
  asm volatile("" : "+v"(x));
  return x;
}

__device__ __forceinline__ unsigned short f2bf(float f) {
  unsigned u = __builtin_bit_cast(unsigned, f);
  unsigned r = (u + 0x7fffu + ((u >> 16) & 1u)) >> 16;
  return (unsigned short)r;
}
__device__ __forceinline__ float bf2f(unsigned short h) {
  unsigned u = ((unsigned)h) << 16;
  return __builtin_bit_cast(float, u);
}

__device__ __forceinline__ void split4(float4 v, u16x4& h, u16x4& l) {
  h.x = f2bf(v.x); l.x = f2bf(v.x - bf2f(h.x));
  h.y = f2bf(v.y); l.y = f2bf(v.y - bf2f(h.y));
  h.z = f2bf(v.z); l.z = f2bf(v.z - bf2f(h.z));
  h.w = f2bf(v.w); l.w = f2bf(v.w - bf2f(h.w));
}

// LDS XOR swizzle: row stride = 40 u16 (80 B = 20 banks, gcd(20,32)=4 -> rows
// r and r+8 alias). XOR the 8-byte chunk index with ((row>>3)&3)<<1 (even, so
// 16B read pairs stay contiguous & aligned): 8-way write conflict -> free 2-way.
__device__ __forceinline__ int swzi(int row, int c8) {
  return row * 40 + ((c8 ^ ((row >> 2) & 6)) << 2);  // u16 index
}

// ================= LayerNorm, numpy-exact fp32 (np.mean pairwise) — FROZEN =================
__global__ __launch_bounds__(64) void ln_np(const float* __restrict__ x,
                                            const float* __restrict__ g,
                                            const float* __restrict__ b,
                                            float* __restrict__ y) {
  __shared__ float xs[EE];
  __shared__ float bc[2];
  long long t = blockIdx.x;
  int lane = threadIdx.x;
#pragma unroll
  for (int m = 0; m < 8; m++) xs[lane + 64 * m] = x[t * EE + lane + 64 * m];
  __syncthreads();
  int l = lane >> 3, a = lane & 7;
  float r = 0.f;
  if (lane < 32) {
    r = xs[l * 128 + a];
#pragma unroll
    for (int m = 1; m < 16; m++) r = r + xs[l * 128 + 8 * m + a];
  }
  r = r + __shfl_xor(r, 1);
  r = r + __shfl_xor(r, 2);
  r = r + __shfl_xor(r, 4);
  r = r + __shfl_xor(r, 8);
  r = r + __shfl_xor(r, 16);
  if (lane == 0) bc[0] = r / 512.0f;
  __syncthreads();
  float mean = bc[0];
  r = 0.f;
  if (lane < 32) {
#pragma unroll
    for (int m = 0; m < 16; m++) {
      float d = sep(xs[l * 128 + 8 * m + a] - mean);
      float s2 = sep(d * d);
      r = (m == 0) ? s2 : (r + s2);
    }
  }
  r = r + __shfl_xor(r, 1);
  r = r + __shfl_xor(r, 2);
  r = r + __shfl_xor(r, 4);
  r = r + __shfl_xor(r, 8);
  r = r + __shfl_xor(r, 16);
  if (lane == 0) bc[1] = r / 512.0f;
  __syncthreads();
  float var = bc[1];
  float rs = 1.0f / sqrtf(var + 1e-5f);
#pragma unroll
  for (int m = 0; m < 8; m++) {
    int i = lane + 64 * m;
    float d = sep(xs[i] - mean);
    float t1 = sep(d * rs);
    float t2 = sep(t1 * g[i]);
    y[t * EE + i] = t2 + b[i];
  }
}

// ================= distances — FROZEN math; s-range split over blockIdx.y =================
__global__ __launch_bounds__(256) void dist_np(const float* __restrict__ nq,
                                               const float* __restrict__ conv_w,
                                               const float* __restrict__ conv_b,
                                               float* __restrict__ dist) {
  int bh = blockIdx.x;
  int b = bh >> 3, h = bh & 7;
  float cb = conv_b[h];
  const float* W = conv_w + (long long)h * EE * 3;
  int s = blockIdx.y * 256 + threadIdx.x;
  float d = cb;
#pragma unroll
  for (int k = 0; k < 3; k++) {
    int t = s - 2 + k;
    if (t < 0) continue;
    const float* row = nq + ((long long)b * SQ + t) * EE;
    float acc = 0.f;
    for (int e = 0; e < EE; e++) acc = __builtin_fmaf(row[e], W[e * 3 + k], acc);
    d = sep(d + acc);
  }
  dist[(long long)bh * SQ + s] = (float)tanh((double)d);
}

// ================= fp32 tiled NT-GEMM — FROZEN DAG (R12, byte-identical) =================
__device__ __forceinline__ float gelu_exact(float x) {
  return 0.5f * x * (1.f + erff(x / 1.41421356237309504880f));
}

template <int ACT, int SPLITK>
__global__ __launch_bounds__(256) void gemm_nt(const float* __restrict__ A, int lda, long long sA,
                                               const float* __restrict__ B, int ldb, long long sB,
                                               const float* __restrict__ bias,
                                               const float* __restrict__ Res,
                                               float* __restrict__ C, int ldc, long long sC,
                                               int K, float alpha) {
  __shared__ float As[16][68];
  __shared__ float Bs[16][68];
  int z = blockIdx.z;
  A += (long long)z * sA;
  B += (long long)z * sB;
  C += (long long)z * sC;
  int m0 = blockIdx.y * 64, n0 = blockIdx.x * 64;
  int tid = threadIdx.x;
  int lr = tid >> 2, lc = tid & 3;
  int tx = tid & 15, ty = tid >> 4;
  float acc[4][4] = {};
  float acc2[4][4] = {};
  const float* Arow = A + (long long)(m0 + lr) * lda + lc * 4;
  const float* Brow = B + (long long)(n0 + lr) * ldb + lc * 4;
  float4 a4 = *(const float4*)(Arow);
  float4 b4 = *(const float4*)(Brow);
  for (int k0 = 0; k0 < K; k0 += 16) {
    __syncthreads();
    As[lc * 4 + 0][lr] = a4.x; As[lc * 4 + 1][lr] = a4.y;
    As[lc * 4 + 2][lr] = a4.z; As[lc * 4 + 3][lr] = a4.w;
    Bs[lc * 4 + 0][lr] = b4.x; Bs[lc * 4 + 1][lr] = b4.y;
    Bs[lc * 4 + 2][lr] = b4.z; Bs[lc * 4 + 3][lr] = b4.w;
    __syncthreads();
    int kn = (k0 + 16 < K) ? (k0 + 16) : k0;
    float4 a4n = *(const float4*)(Arow + kn);
    float4 b4n = *(const float4*)(Brow + kn);
    float(*tgt)[4] = (SPLITK > 0 && k0 >= SPLITK) ? acc2 : acc;
#pragma unroll
    for (int kk = 0; kk < 16; kk++) {
      float4 av = *(const float4*)&As[kk][ty * 4];
      float4 bv = *(const float4*)&Bs[kk][tx * 4];
      float a[4] = {av.x, av.y, av.z, av.w};
      float bb[4] = {bv.x, bv.y, bv.z, bv.w};
#pragma unroll
      for (int i = 0; i < 4; i++)
#pragma unroll
        for (int j = 0; j < 4; j++) tgt[i][j] += a[i] * bb[j];
    }
    a4 = a4n;
    b4 = b4n;
  }
  if (SPLITK > 0) {
#pragma unroll
    for (int i = 0; i < 4; i++)
#pragma unroll
      for (int j = 0; j < 4; j++) acc[i][j] = sep(acc[i][j]) + acc2[i][j];
  }
  float4 bias4 = make_float4(0.f, 0.f, 0.f, 0.f);
  if (ACT != 2 && bias) bias4 = *(const float4*)(bias + n0 + tx * 4);
#pragma unroll
  for (int i = 0; i < 4; i++) {
    int row = m0 + ty * 4 + i;
    float o[4];
    if (ACT == 2) {
#pragma unroll
      for (int j = 0; j < 4; j++) o[j] = acc[i][j] / alpha;
    } else {
      o[0] = sep(acc[i][0] * alpha) + bias4.x;
      o[1] = sep(acc[i][1] * alpha) + bias4.y;
      o[2] = sep(acc[i][2] * alpha) + bias4.z;
      o[3] = sep(acc[i][3] * alpha) + bias4.w;
    }
    if (ACT == 1) {
#pragma unroll
      for (int j = 0; j < 4; j++) o[j] = gelu_exact(o[j]);
    }
    if (Res) {
      float4 r4 = *(const float4*)(Res + (long long)row * ldc + n0 + tx * 4);
      o[0] = sep(o[0]) + r4.x; o[1] = sep(o[1]) + r4.y;
      o[2] = sep(o[2]) + r4.z; o[3] = sep(o[3]) + r4.w;
    }
    *(float4*)(C + (long long)row * ldc + n0 + tx * 4) = make_float4(o[0], o[1], o[2], o[3]);
  }
}

// ================= gated row sums: np.sum pairwise(1024) — FROZEN =================
__global__ __launch_bounds__(64) void rowsum_np(const float* __restrict__ scores,
                                                const float* __restrict__ dist,
                                                float* __restrict__ invrs) {
  __shared__ float wsm[SQ];
  int i = blockIdx.x;
  int z = blockIdx.y;
  int b = z >> 3;
  const float* srow = scores + ((long long)b * SQ + i) * SQ;
  const float* dz = dist + (long long)z * SQ;
  float di = dz[i];
  int lane = threadIdx.x;
#pragma unroll
  for (int m = 0; m < 16; m++) {
    int j = lane + 64 * m;
    float e = (float)exp((double)(dz[j] - di));
    float gg = 1.f / (1.f + e);
    wsm[j] = srow[j] * gg;
  }
  __syncthreads();
  int l = lane >> 3, a = lane & 7;
  float r = wsm[l * 128 + a];
#pragma unroll
  for (int m = 1; m < 16; m++) r = r + wsm[l * 128 + 8 * m + a];
  r = r + __shfl_xor(r, 1);
  r = r + __shfl_xor(r, 2);
  r = r + __shfl_xor(r, 4);
  r = r + __shfl_xor(r, 8);
  r = r + __shfl_xor(r, 16);
  r = r + __shfl_xor(r, 32);
  if (lane == 0) invrs[(long long)z * SQ + i] = 1.f / (r + 1e-12f);
}

// ================= V transpose + bf16 hi/lo split:  VhT/VlT[b][e][j] = split(V[b][j][e]) =================
__global__ __launch_bounds__(256) void vsplit_t(const float* __restrict__ qkv,
                                                unsigned short* __restrict__ VhT,
                                                unsigned short* __restrict__ VlT) {
  __shared__ float tile[64][65];
  int b = blockIdx.z;
  int j0 = blockIdx.x * 64;  // S tile
  int e0 = blockIdx.y * 64;  // E tile
  const float* V = qkv + (long long)b * SQ * (3 * EE) + 2 * EE;
  unsigned short* Vh = VhT + (long long)b * EE * SQ;
  unsigned short* Vl = VlT + (long long)b * EE * SQ;
  int tx = threadIdx.x & 15, ty = threadIdx.x >> 4;
#pragma unroll
  for (int r = 0; r < 4; r++) {
    int j = j0 + ty + r * 16;
    float4 v = *(const float4*)(V + (long long)j * (3 * EE) + e0 + tx * 4);
    tile[ty + r * 16][tx * 4 + 0] = v.x;
    tile[ty + r * 16][tx * 4 + 1] = v.y;
    tile[ty + r * 16][tx * 4 + 2] = v.z;
    tile[ty + r * 16][tx * 4 + 3] = v.w;
  }
  __syncthreads();
#pragma unroll
  for (int r = 0; r < 4; r++) {
    int el = ty + r * 16;
    float4 f;
    f.x = tile[tx * 4 + 0][el];
    f.y = tile[tx * 4 + 1][el];
    f.z = tile[tx * 4 + 2][el];
    f.w = tile[tx * 4 + 3][el];
    u16x4 hh, ll;
    split4(f, hh, ll);
    long long o = (long long)(e0 + el) * SQ + j0 + tx * 4;
    *(u16x4*)(Vh + o) = hh;
    *(u16x4*)(Vl + o) = ll;
  }
}

// ================= ctx GEMM via bf16x3 MFMA — BN=256, fast gate, swizzled LDS =================
// ctx[b,h,i,e] = sum_j ((scores[i,j]*sigmoid(di-dj))*inv_i) * V[j,e]
// Gate uses __expf + v_rcp (rel err ~5e-7, well under the bf16x3 split error
// ~8e-6 already proven to pass). B pre-split/pre-transposed by vsplit_t.
// Tile 64x256, 4 waves (each 64 cols), K-step 32, mfma 16x16x32.
__global__ __launch_bounds__(256) void ctx_bf3(const float* __restrict__ scores,
                                               const float* __restrict__ dist,
                                               const float* __restrict__ invrs,
                                               const unsigned short* __restrict__ VhT,
                                               const unsigned short* __restrict__ VlT,
                                               float* __restrict__ ctx) {
  constexpr int BN = 256;
  constexpr int NF = 4;  // 4 n-frags per wave (16 cols each)
  __shared__ __align__(16) unsigned short Ah[64 * 40], Al[64 * 40];
  __shared__ __align__(16) unsigned short Bh[BN * 40], Bl[BN * 40];
  int z = blockIdx.z, b = z >> 3, h = z & 7;
  const float* Sb = scores + (long long)b * SQ * SQ;
  const unsigned short* Vh = VhT + (long long)b * EE * SQ;
  const unsigned short* Vl = VlT + (long long)b * EE * SQ;
  float* C = ctx + (long long)b * SQ * (NH * EE) + h * EE;
  const float* dz = dist + (long long)z * SQ;
  int m0 = blockIdx.y * 64, n0 = blockIdx.x * BN;
  int tid = threadIdx.x;
  int wave = tid >> 6, lane = tid & 63;
  int quad = lane >> 4, l16 = lane & 15;
  int colb0 = wave * 64;
  f32x4 acc[4][NF];
#pragma unroll
  for (int mf = 0; mf < 4; mf++)
#pragma unroll
    for (int nf = 0; nf < NF; nf++) acc[mf][nf] = (f32x4)(0.f);

  // A staging: row aam, k-chunks (aakc + r*4)*4, r=0..1  -> 8 floats/thread/K-step
  int aam = tid & 63, aakc = tid >> 6;
  float di = dz[m0 + aam];
  float inv = invrs[(long long)z * SQ + m0 + aam];
  const float* Srow = Sb + (long long)(m0 + aam) * SQ;
  // B staging: one row per thread (brow = output col e), 4 u16x8 chunks per buffer
  int brow = tid;
  const unsigned short* VhRow = Vh + (long long)(n0 + brow) * SQ;
  const unsigned short* VlRow = Vl + (long long)(n0 + brow) * SQ;

  u16x4 aH[2], aL[2];
  u16x8 bH[4], bL[4];

  auto loadconv = [&](int kb) {
#pragma unroll
    for (int r = 0; r < 2; r++) {
      int kc = aakc + r * 4;
      float4 s4 = *(const float4*)(Srow + kb + kc * 4);
      float4 d4 = *(const float4*)(dz + kb + kc * 4);
      float4 a;
      a.x = (s4.x * __builtin_amdgcn_rcpf(1.f + __expf(d4.x - di))) * inv;
      a.y = (s4.y * __builtin_amdgcn_rcpf(1.f + __expf(d4.y - di))) * inv;
      a.z = (s4.z * __builtin_amdgcn_rcpf(1.f + __expf(d4.z - di))) * inv;
      a.w = (s4.w * __builtin_amdgcn_rcpf(1.f + __expf(d4.w - di))) * inv;
      split4(a, aH[r], aL[r]);
    }
#pragma unroll
    for (int c = 0; c < 4; c++) {
      bH[c] = *(const u16x8*)(VhRow + kb + c * 8);
      bL[c] = *(const u16x8*)(VlRow + kb + c * 8);
    }
  };

  loadconv(0);
  for (int k0 = 0; k0 < SQ; k0 += 32) {
    __syncthreads();
#pragma unroll
    for (int r = 0; r < 2; r++) {
      *(u16x4*)&Ah[swzi(aam, aakc + r * 4)] = aH[r];
      *(u16x4*)&Al[swzi(aam, aakc + r * 4)] = aL[r];
    }
#pragma unroll
    for (int c = 0; c < 4; c++) {
      *(u16x8*)&Bh[swzi(brow, 2 * c)] = bH[c];
      *(u16x8*)&Bl[swzi(brow, 2 * c)] = bL[c];
    }
    __syncthreads();
    int kn = (k0 + 32 < SQ) ? (k0 + 32) : k0;  // clamped dummy reload
    loadconv(kn);
    bfrag bhf[NF], blf[NF];
#pragma unroll
    for (int nf = 0; nf < NF; nf++) {
      bhf[nf] = *(const bfrag*)&Bh[swzi(colb0 + nf * 16 + l16, quad * 2)];
      blf[nf] = *(const bfrag*)&Bl[swzi(colb0 + nf * 16 + l16, quad * 2)];
    }
#pragma unroll
    for (int mf = 0; mf < 4; mf++) {
      bfrag ah = *(const bfrag*)&Ah[swzi(mf * 16 + l16, quad * 2)];
      bfrag al = *(const bfrag*)&Al[swzi(mf * 16 + l16, quad * 2)];
#pragma unroll
      for (int nf = 0; nf < NF; nf++) {
        acc[mf][nf] = __builtin_amdgcn_mfma_f32_16x16x32_bf16(al, bhf[nf], acc[mf][nf], 0, 0, 0);
        acc[mf][nf] = __builtin_amdgcn_mfma_f32_16x16x32_bf16(ah, blf[nf], acc[mf][nf], 0, 0, 0);
        acc[mf][nf] = __builtin_amdgcn_mfma_f32_16x16x32_bf16(ah, bhf[nf], acc[mf][nf], 0, 0, 0);
      }
    }
  }
  // epilogue: C/D layout row = quad*4 + r, col = l16
#pragma unroll
  for (int mf = 0; mf < 4; mf++) {
#pragma unroll
    for (int nf = 0; nf < NF; nf++) {
      int col = n0 + colb0 + nf * 16 + l16;
#pragma unroll
      for (int r = 0; r < 4; r++) {
        int row = m0 + mf * 16 + quad * 4 + r;
        C[(long long)row * (NH * EE) + col] = acc[mf][nf][r];
      }
    }
  }
}

// ================= bf16x3 MFMA NT-GEMM (numerator-side only) =================
// C = act(A@B^T + bias) (+Res). fp32 split into hi/lo bf16; 3 MFMA terms per
// product (rel err ~2^-17). Tile 64 x BN, 4 waves, K-step 32, mfma 16x16x32.
// LDS swizzled (pure position permutation — numerics byte-identical).
template <int ACT, int BN>
__global__ __launch_bounds__(256) void gemm_bf3(const float* __restrict__ A, int lda,
                                                const float* __restrict__ B, int ldb,
                                                const float* __restrict__ bias,
                                                const float* __restrict__ Res,
                                                float* __restrict__ C, int ldc, int K) {
  constexpr int NF = BN / 64;        // n-frags per wave (16 cols each)
  constexpr int NREPB = BN / 32;     // B staging reps (float4 per thread)
  __shared__ __align__(16) unsigned short Ah[64 * 40], Al[64 * 40];
  __shared__ __align__(16) unsigned short Bh[BN * 40], Bl[BN * 40];
  int m0 = blockIdx.y * 64, n0 = blockIdx.x * BN;
  int tid = threadIdx.x;
  int wave = tid >> 6, lane = tid & 63;
  int quad = lane >> 4, l16 = lane & 15;
  int colb0 = wave * (BN / 4);
  f32x4 acc[4][NF];
#pragma unroll
  for (int mf = 0; mf < 4; mf++)
#pragma unroll
    for (int nf = 0; nf < NF; nf++) acc[mf][nf] = (f32x4)(0.f);

  int aam = tid & 63, aakc = tid >> 6;            // +r*4 on kc per rep
  float4 aldg[2], bldg[NREPB];
#pragma unroll
  for (int r = 0; r < 2; r++)
    aldg[r] = *(const float4*)(A + (long long)(m0 + aam) * lda + (aakc + r * 4) * 4);
  int bbn = tid & (BN - 1), bbkc = tid / BN;
#pragma unroll
  for (int r = 0; r < NREPB; r++)
    bldg[r] = *(const float4*)(B + (long long)(n0 + bbn) * ldb + (bbkc + r * (256 / BN)) * 4);

  for (int k0 = 0; k0 < K; k0 += 32) {
    __syncthreads();
#pragma unroll
    for (int r = 0; r < 2; r++) {
      float4 v = aldg[r];
      int kc = aakc + r * 4;
      u16x4 h, l;
      split4(v, h, l);
      *(u16x4*)&Ah[swzi(aam, kc)] = h;
      *(u16x4*)&Al[swzi(aam, kc)] = l;
    }
#pragma unroll
    for (int r = 0; r < NREPB; r++) {
      float4 v = bldg[r];
      int kc = bbkc + r * (256 / BN);
      u16x4 h, l;
      split4(v, h, l);
      *(u16x4*)&Bh[swzi(bbn, kc)] = h;
      *(u16x4*)&Bl[swzi(bbn, kc)] = l;
    }
    __syncthreads();
    int kn = (k0 + 32 < K) ? (k0 + 32) : k0;  // clamped dummy reload
#pragma unroll
    for (int r = 0; r < 2; r++)
      aldg[r] = *(const float4*)(A + (long long)(m0 + aam) * lda + kn + (aakc + r * 4) * 4);
#pragma unroll
    for (int r = 0; r < NREPB; r++)
      bldg[r] = *(const float4*)(B + (long long)(n0 + bbn) * ldb + kn + (bbkc + r * (256 / BN)) * 4);
    bfrag bh[NF], bl[NF];
#pragma unroll
    for (int nf = 0; nf < NF; nf++) {
      bh[nf] = *(const bfrag*)&Bh[swzi(colb0 + nf * 16 + l16, quad * 2)];
      bl[nf] = *(const bfrag*)&Bl[swzi(colb0 + nf * 16 + l16, quad * 2)];
    }
#pragma unroll
    for (int mf = 0; mf < 4; mf++) {
      bfrag ah = *(const bfrag*)&Ah[swzi(mf * 16 + l16, quad * 2)];
      bfrag al = *(const bfrag*)&Al[swzi(mf * 16 + l16, quad * 2)];
#pragma unroll
      for (int nf = 0; nf < NF; nf++) {
        acc[mf][nf] = __builtin_amdgcn_mfma_f32_16x16x32_bf16(al, bh[nf], acc[mf][nf], 0, 0, 0);
        acc[mf][nf] = __builtin_amdgcn_mfma_f32_16x16x32_bf16(ah, bl[nf], acc[mf][nf], 0, 0, 0);
        acc[mf][nf] = __builtin_amdgcn_mfma_f32_16x16x32_bf16(ah, bh[nf], acc[mf][nf], 0, 0, 0);
      }
    }
  }
  // epilogue: C/D layout row = quad*4 + r, col = lane&15
#pragma unroll
  for (int mf = 0; mf < 4; mf++) {
#pragma unroll
    for (int nf = 0; nf < NF; nf++) {
      int col = n0 + colb0 + nf * 16 + l16;
      float bi = bias ? bias[col] : 0.f;
#pragma unroll
      for (int r = 0; r < 4; r++) {
        int row = m0 + mf * 16 + quad * 4 + r;
        float o = acc[mf][nf][r] + bi;
        if (ACT == 1) o = gelu_exact(o);
        if (Res) o = o + Res[(long long)row * ldc + col];
        C[(long long)row * ldc + col] = o;
      }
    }
  }
}

extern "C" void kernel_launch(void* const* d_in, const int* in_sizes, int n_in,
                              void* d_out, int out_size, void* d_ws, size_t ws_size,
                              hipStream_t stream) {
  const float* query     = (const float*)d_in[0];
  const float* ln1_g     = (const float*)d_in[1];
  const float* ln1_b     = (const float*)d_in[2];
  const float* in_proj_w = (const float*)d_in[3];
  const float* in_proj_b = (const float*)d_in[4];
  const float* out_w     = (const float*)d_in[5];
  const float* out_b     = (const float*)d_in[6];
  const float* conv_w    = (const float*)d_in[7];
  const float* conv_b    = (const float*)d_in[8];
  const float* ln2_g     = (const float*)d_in[9];
  const float* ln2_b     = (const float*)d_in[10];
  const float* mlp_w1    = (const float*)d_in[11];
  const float* mlp_b1    = (const float*)d_in[12];
  const float* mlp_w2    = (const float*)d_in[13];
  const float* mlp_b2    = (const float*)d_in[14];
  float* out = (float*)d_out;
  char* ws = (char*)d_ws;

  // R7-exact layout: peak 112.25 MiB (proven safe)
  float* nq     = (float*)(ws + 0);                      // 8 MiB
  float* qkv    = (float*)(ws + (8ull << 20));           // 24 MiB
  float* dist   = (float*)(ws + (32ull << 20));          // 128 KiB
  float* invrs  = (float*)(ws + (32ull << 20) + 131072); // 128 KiB
  float* scores = (float*)(ws + (32ull << 20) + 262144); // 16 MiB
  float* ctx    = (float*)(ws + (48ull << 20) + 262144); // 64 MiB -> 112.25 MiB
  float* ln2out = scores;                                // reuse
  float* hbuf   = nq;                                    // reuse nq+qkv (32 MiB)
  // VhT/VlT live in the dead nq region (nq unused between qkv-GEMM and MLP1's hbuf reuse):
  unsigned short* VhT = (unsigned short*)(ws + 0);             // 4 MiB
  unsigned short* VlT = (unsigned short*)(ws + (4ull << 20));  // 4 MiB (exactly fills nq's 8 MiB)

  // 1. LN1 (frozen)
  ln_np<<<dim3(NB * SQ), 64, 0, stream>>>(query, ln1_g, ln1_b, nq);
  // 2. distances (frozen)
  dist_np<<<dim3(NB * NH, 4), 256, 0, stream>>>(nq, conv_w, conv_b, dist);
  // 3. qkv (frozen chain)  M=4096 N=1536 K=512
  gemm_nt<0, 384><<<dim3(24, 64, 1), 256, 0, stream>>>(nq, EE, 0, in_proj_w, EE, 0,
                                                       in_proj_b, nullptr, qkv, 3 * EE, 0, EE, 1.f);
  // 3b. V transpose + bf16 hi/lo split (nq is dead from here until step 9)
  vsplit_t<<<dim3(16, 8, NB), 256, 0, stream>>>(qkv, VhT, VlT);
  // 4. scores (frozen chain + true division)  M=N=1024 K=512, batched B
  gemm_nt<2, 384><<<dim3(16, 16, NB), 256, 0, stream>>>(
      qkv, 3 * EE, (long long)SQ * 3 * EE, qkv + EE, 3 * EE, (long long)SQ * 3 * EE,
      nullptr, nullptr, scores, SQ, (long long)SQ * SQ, EE, sqrtf(512.0f));
  // 5. gated row sums (frozen)
  rowsum_np<<<dim3(SQ, NB * NH), 64, 0, stream>>>(scores, dist, invrs);
  // 6. ctx via bf16x3 MFMA  M=1024 N=512 K=1024, z = B*H, BN=256
  ctx_bf3<<<dim3(EE / 256, 16, NB * NH), 256, 0, stream>>>(scores, dist, invrs, VhT, VlT, ctx);
  // 7. attn_out + residual (MFMA bf16x3)  M=4096 N=512 K=4096
  gemm_bf3<0, 64><<<dim3(8, 64), 256, 0, stream>>>(ctx, NH * EE, out_w, NH * EE,
                                                   out_b, query, out, EE, NH * EE);
  // 8. LN2
  ln_np<<<dim3(NB * SQ), 64, 0, stream>>>(out, ln2_g, ln2_b, ln2out);
  // 9. MLP1 + gelu (MFMA bf16x3)  M=4096 N=2048 K=512
  gemm_bf3<1, 128><<<dim3(16, 64), 256, 0, stream>>>(ln2out, EE, mlp_w1, EE,
                                                     mlp_b1, nullptr, hbuf, 4 * EE, EE);
  // 10. MLP2 + residual (MFMA bf16x3)  M=4096 N=512 K=2048
  gemm_bf3<0, 64><<<dim3(8, 64), 256, 0, stream>>>(hbuf, 4 * EE, mlp_w2, 4 * EE,
                                                   mlp_b2, out, out, EE, 4 * EE);
}

// Round 3
// 748.723 us; speedup vs baseline: 1.7142x; 1.3251x over previous
//
#include <hip/hip_runtime.h>
#include <math.h>

#define SQ 1024  // S
#define EE 512   // E
#define NB 4     // B
#define NH 8     // H

typedef __attribute__((ext_vector_type(8))) short bfrag;       // 8 bf16 (4 VGPRs)
typedef __attribute__((ext_vector_type(4))) float f32x4;       // MFMA C/D
typedef __attribute__((ext_vector_type(4))) unsigned short u16x4;
typedef __attribute__((ext_vector_type(8))) unsigned short u16x8;

typedef __attribute__((address_space(3))) unsigned int lds_u32;
typedef const __attribute__((address_space(1))) unsigned int glb_u32;

// Optimization barrier: forces materialization (rounding) so the compiler
// cannot FMA-contract or reassociate across numpy's op boundaries.
__device__ __forceinline__ float sep(float x) {
  asm volatile("" : "+v"(x));
  return x;
}

__device__ __forceinline__ unsigned short f2bf(float f) {
  unsigned u = __builtin_bit_cast(unsigned, f);
  unsigned r = (u + 0x7fffu + ((u >> 16) & 1u)) >> 16;
  return (unsigned short)r;
}
__device__ __forceinline__ float bf2f(unsigned short h) {
  unsigned u = ((unsigned)h) << 16;
  return __builtin_bit_cast(float, u);
}

__device__ __forceinline__ void split4(float4 v, u16x4& h, u16x4& l) {
  h.x = f2bf(v.x); l.x = f2bf(v.x - bf2f(h.x));
  h.y = f2bf(v.y); l.y = f2bf(v.y - bf2f(h.y));
  h.z = f2bf(v.z); l.z = f2bf(v.z - bf2f(h.z));
  h.w = f2bf(v.w); l.w = f2bf(v.w - bf2f(h.w));
}

// LDS XOR swizzle for ctx_bf3's reg-staged tiles (row stride 40 u16).
__device__ __forceinline__ int swzi(int row, int c8) {
  return row * 40 + ((c8 ^ ((row >> 2) & 6)) << 2);  // u16 index
}

// ================= LayerNorm, numpy-exact fp32 (np.mean pairwise) — FROZEN =================
__global__ __launch_bounds__(64) void ln_np(const float* __restrict__ x,
                                            const float* __restrict__ g,
                                            const float* __restrict__ b,
                                            float* __restrict__ y) {
  __shared__ float xs[EE];
  __shared__ float bc[2];
  long long t = blockIdx.x;
  int lane = threadIdx.x;
#pragma unroll
  for (int m = 0; m < 8; m++) xs[lane + 64 * m] = x[t * EE + lane + 64 * m];
  __syncthreads();
  int l = lane >> 3, a = lane & 7;
  float r = 0.f;
  if (lane < 32) {
    r = xs[l * 128 + a];
#pragma unroll
    for (int m = 1; m < 16; m++) r = r + xs[l * 128 + 8 * m + a];
  }
  r = r + __shfl_xor(r, 1);
  r = r + __shfl_xor(r, 2);
  r = r + __shfl_xor(r, 4);
  r = r + __shfl_xor(r, 8);
  r = r + __shfl_xor(r, 16);
  if (lane == 0) bc[0] = r / 512.0f;
  __syncthreads();
  float mean = bc[0];
  r = 0.f;
  if (lane < 32) {
#pragma unroll
    for (int m = 0; m < 16; m++) {
      float d = sep(xs[l * 128 + 8 * m + a] - mean);
      float s2 = sep(d * d);
      r = (m == 0) ? s2 : (r + s2);
    }
  }
  r = r + __shfl_xor(r, 1);
  r = r + __shfl_xor(r, 2);
  r = r + __shfl_xor(r, 4);
  r = r + __shfl_xor(r, 8);
  r = r + __shfl_xor(r, 16);
  if (lane == 0) bc[1] = r / 512.0f;
  __syncthreads();
  float var = bc[1];
  float rs = 1.0f / sqrtf(var + 1e-5f);
#pragma unroll
  for (int m = 0; m < 8; m++) {
    int i = lane + 64 * m;
    float d = sep(xs[i] - mean);
    float t1 = sep(d * rs);
    float t2 = sep(t1 * g[i]);
    y[t * EE + i] = t2 + b[i];
  }
}

// ===== LayerNorm with split bf16 hi/lo output (same frozen math, split store) =====
__global__ __launch_bounds__(64) void ln_np_s(const float* __restrict__ x,
                                              const float* __restrict__ g,
                                              const float* __restrict__ b,
                                              unsigned short* __restrict__ yh,
                                              unsigned short* __restrict__ yl) {
  __shared__ float xs[EE];
  __shared__ float bc[2];
  long long t = blockIdx.x;
  int lane = threadIdx.x;
#pragma unroll
  for (int m = 0; m < 8; m++) xs[lane + 64 * m] = x[t * EE + lane + 64 * m];
  __syncthreads();
  int l = lane >> 3, a = lane & 7;
  float r = 0.f;
  if (lane < 32) {
    r = xs[l * 128 + a];
#pragma unroll
    for (int m = 1; m < 16; m++) r = r + xs[l * 128 + 8 * m + a];
  }
  r = r + __shfl_xor(r, 1);
  r = r + __shfl_xor(r, 2);
  r = r + __shfl_xor(r, 4);
  r = r + __shfl_xor(r, 8);
  r = r + __shfl_xor(r, 16);
  if (lane == 0) bc[0] = r / 512.0f;
  __syncthreads();
  float mean = bc[0];
  r = 0.f;
  if (lane < 32) {
#pragma unroll
    for (int m = 0; m < 16; m++) {
      float d = sep(xs[l * 128 + 8 * m + a] - mean);
      float s2 = sep(d * d);
      r = (m == 0) ? s2 : (r + s2);
    }
  }
  r = r + __shfl_xor(r, 1);
  r = r + __shfl_xor(r, 2);
  r = r + __shfl_xor(r, 4);
  r = r + __shfl_xor(r, 8);
  r = r + __shfl_xor(r, 16);
  if (lane == 0) bc[1] = r / 512.0f;
  __syncthreads();
  float var = bc[1];
  float rs = 1.0f / sqrtf(var + 1e-5f);
#pragma unroll
  for (int m = 0; m < 8; m++) {
    int i = lane + 64 * m;
    float d = sep(xs[i] - mean);
    float t1 = sep(d * rs);
    float t2 = sep(t1 * g[i]);
    float o = t2 + b[i];
    unsigned short hh = f2bf(o);
    yh[t * EE + i] = hh;
    yl[t * EE + i] = f2bf(o - bf2f(hh));
  }
}

// ================= distances — FROZEN math; s-range split over blockIdx.y =================
__global__ __launch_bounds__(256) void dist_np(const float* __restrict__ nq,
                                               const float* __restrict__ conv_w,
                                               const float* __restrict__ conv_b,
                                               float* __restrict__ dist) {
  int bh = blockIdx.x;
  int b = bh >> 3, h = bh & 7;
  float cb = conv_b[h];
  const float* W = conv_w + (long long)h * EE * 3;
  int s = blockIdx.y * 256 + threadIdx.x;
  float d = cb;
#pragma unroll
  for (int k = 0; k < 3; k++) {
    int t = s - 2 + k;
    if (t < 0) continue;
    const float* row = nq + ((long long)b * SQ + t) * EE;
    float acc = 0.f;
    for (int e = 0; e < EE; e++) acc = __builtin_fmaf(row[e], W[e * 3 + k], acc);
    d = sep(d + acc);
  }
  dist[(long long)bh * SQ + s] = (float)tanh((double)d);
}

// ================= fp32 tiled NT-GEMM — FROZEN DAG (R12, byte-identical) =================
__device__ __forceinline__ float gelu_exact(float x) {
  return 0.5f * x * (1.f + erff(x / 1.41421356237309504880f));
}

template <int ACT, int SPLITK>
__global__ __launch_bounds__(256) void gemm_nt(const float* __restrict__ A, int lda, long long sA,
                                               const float* __restrict__ B, int ldb, long long sB,
                                               const float* __restrict__ bias,
                                               const float* __restrict__ Res,
                                               float* __restrict__ C, int ldc, long long sC,
                                               int K, float alpha) {
  __shared__ float As[16][68];
  __shared__ float Bs[16][68];
  int z = blockIdx.z;
  A += (long long)z * sA;
  B += (long long)z * sB;
  C += (long long)z * sC;
  int m0 = blockIdx.y * 64, n0 = blockIdx.x * 64;
  int tid = threadIdx.x;
  int lr = tid >> 2, lc = tid & 3;
  int tx = tid & 15, ty = tid >> 4;
  float acc[4][4] = {};
  float acc2[4][4] = {};
  const float* Arow = A + (long long)(m0 + lr) * lda + lc * 4;
  const float* Brow = B + (long long)(n0 + lr) * ldb + lc * 4;
  float4 a4 = *(const float4*)(Arow);
  float4 b4 = *(const float4*)(Brow);
  for (int k0 = 0; k0 < K; k0 += 16) {
    __syncthreads();
    As[lc * 4 + 0][lr] = a4.x; As[lc * 4 + 1][lr] = a4.y;
    As[lc * 4 + 2][lr] = a4.z; As[lc * 4 + 3][lr] = a4.w;
    Bs[lc * 4 + 0][lr] = b4.x; Bs[lc * 4 + 1][lr] = b4.y;
    Bs[lc * 4 + 2][lr] = b4.z; Bs[lc * 4 + 3][lr] = b4.w;
    __syncthreads();
    int kn = (k0 + 16 < K) ? (k0 + 16) : k0;
    float4 a4n = *(const float4*)(Arow + kn);
    float4 b4n = *(const float4*)(Brow + kn);
    float(*tgt)[4] = (SPLITK > 0 && k0 >= SPLITK) ? acc2 : acc;
#pragma unroll
    for (int kk = 0; kk < 16; kk++) {
      float4 av = *(const float4*)&As[kk][ty * 4];
      float4 bv = *(const float4*)&Bs[kk][tx * 4];
      float a[4] = {av.x, av.y, av.z, av.w};
      float bb[4] = {bv.x, bv.y, bv.z, bv.w};
#pragma unroll
      for (int i = 0; i < 4; i++)
#pragma unroll
        for (int j = 0; j < 4; j++) tgt[i][j] += a[i] * bb[j];
    }
    a4 = a4n;
    b4 = b4n;
  }
  if (SPLITK > 0) {
#pragma unroll
    for (int i = 0; i < 4; i++)
#pragma unroll
      for (int j = 0; j < 4; j++) acc[i][j] = sep(acc[i][j]) + acc2[i][j];
  }
  float4 bias4 = make_float4(0.f, 0.f, 0.f, 0.f);
  if (ACT != 2 && bias) bias4 = *(const float4*)(bias + n0 + tx * 4);
#pragma unroll
  for (int i = 0; i < 4; i++) {
    int row = m0 + ty * 4 + i;
    float o[4];
    if (ACT == 2) {
#pragma unroll
      for (int j = 0; j < 4; j++) o[j] = acc[i][j] / alpha;
    } else {
      o[0] = sep(acc[i][0] * alpha) + bias4.x;
      o[1] = sep(acc[i][1] * alpha) + bias4.y;
      o[2] = sep(acc[i][2] * alpha) + bias4.z;
      o[3] = sep(acc[i][3] * alpha) + bias4.w;
    }
    if (ACT == 1) {
#pragma unroll
      for (int j = 0; j < 4; j++) o[j] = gelu_exact(o[j]);
    }
    if (Res) {
      float4 r4 = *(const float4*)(Res + (long long)row * ldc + n0 + tx * 4);
      o[0] = sep(o[0]) + r4.x; o[1] = sep(o[1]) + r4.y;
      o[2] = sep(o[2]) + r4.z; o[3] = sep(o[3]) + r4.w;
    }
    *(float4*)(C + (long long)row * ldc + n0 + tx * 4) = make_float4(o[0], o[1], o[2], o[3]);
  }
}

// ================= gated row sums: np.sum pairwise(1024) — FROZEN =================
__global__ __launch_bounds__(64) void rowsum_np(const float* __restrict__ scores,
                                                const float* __restrict__ dist,
                                                float* __restrict__ invrs) {
  __shared__ float wsm[SQ];
  int i = blockIdx.x;
  int z = blockIdx.y;
  int b = z >> 3;
  const float* srow = scores + ((long long)b * SQ + i) * SQ;
  const float* dz = dist + (long long)z * SQ;
  float di = dz[i];
  int lane = threadIdx.x;
#pragma unroll
  for (int m = 0; m < 16; m++) {
    int j = lane + 64 * m;
    float e = (float)exp((double)(dz[j] - di));
    float gg = 1.f / (1.f + e);
    wsm[j] = srow[j] * gg;
  }
  __syncthreads();
  int l = lane >> 3, a = lane & 7;
  float r = wsm[l * 128 + a];
#pragma unroll
  for (int m = 1; m < 16; m++) r = r + wsm[l * 128 + 8 * m + a];
  r = r + __shfl_xor(r, 1);
  r = r + __shfl_xor(r, 2);
  r = r + __shfl_xor(r, 4);
  r = r + __shfl_xor(r, 8);
  r = r + __shfl_xor(r, 16);
  r = r + __shfl_xor(r, 32);
  if (lane == 0) invrs[(long long)z * SQ + i] = 1.f / (r + 1e-12f);
}

// ================= V transpose + bf16 hi/lo split:  VhT/VlT[b][e][j] = split(V[b][j][e]) =================
__global__ __launch_bounds__(256) void vsplit_t(const float* __restrict__ qkv,
                                                unsigned short* __restrict__ VhT,
                                                unsigned short* __restrict__ VlT) {
  __shared__ float tile[64][65];
  int b = blockIdx.z;
  int j0 = blockIdx.x * 64;  // S tile
  int e0 = blockIdx.y * 64;  // E tile
  const float* V = qkv + (long long)b * SQ * (3 * EE) + 2 * EE;
  unsigned short* Vh = VhT + (long long)b * EE * SQ;
  unsigned short* Vl = VlT + (long long)b * EE * SQ;
  int tx = threadIdx.x & 15, ty = threadIdx.x >> 4;
#pragma unroll
  for (int r = 0; r < 4; r++) {
    int j = j0 + ty + r * 16;
    float4 v = *(const float4*)(V + (long long)j * (3 * EE) + e0 + tx * 4);
    tile[ty + r * 16][tx * 4 + 0] = v.x;
    tile[ty + r * 16][tx * 4 + 1] = v.y;
    tile[ty + r * 16][tx * 4 + 2] = v.z;
    tile[ty + r * 16][tx * 4 + 3] = v.w;
  }
  __syncthreads();
#pragma unroll
  for (int r = 0; r < 4; r++) {
    int el = ty + r * 16;
    float4 f;
    f.x = tile[tx * 4 + 0][el];
    f.y = tile[tx * 4 + 1][el];
    f.z = tile[tx * 4 + 2][el];
    f.w = tile[tx * 4 + 3][el];
    u16x4 hh, ll;
    split4(f, hh, ll);
    long long o = (long long)(e0 + el) * SQ + j0 + tx * 4;
    *(u16x4*)(Vh + o) = hh;
    *(u16x4*)(Vl + o) = ll;
  }
}

// ===== flat fp32 -> bf16 hi/lo split (weights); n4 = count/4 =====
__global__ __launch_bounds__(256) void wsplit(const float* __restrict__ W,
                                              unsigned short* __restrict__ Wh,
                                              unsigned short* __restrict__ Wl, int n4) {
  int i = blockIdx.x * 256 + threadIdx.x;
  if (i >= n4) return;
  float4 v = *(const float4*)(W + (long long)i * 4);
  u16x4 h, l;
  split4(v, h, l);
  *(u16x4*)(Wh + (long long)i * 4) = h;
  *(u16x4*)(Wl + (long long)i * 4) = l;
}

// ================= ctx GEMM via bf16x3 MFMA — BN=256, fast gate, swizzled LDS =================
// Epilogue now writes ctx pre-split (bf16 hi/lo) for the downstream DMA GEMM.
__global__ __launch_bounds__(256) void ctx_bf3(const float* __restrict__ scores,
                                               const float* __restrict__ dist,
                                               const float* __restrict__ invrs,
                                               const unsigned short* __restrict__ VhT,
                                               const unsigned short* __restrict__ VlT,
                                               unsigned short* __restrict__ Ch,
                                               unsigned short* __restrict__ Cl) {
  constexpr int BN = 256;
  constexpr int NF = 4;  // 4 n-frags per wave (16 cols each)
  __shared__ __align__(16) unsigned short Ah[64 * 40], Al[64 * 40];
  __shared__ __align__(16) unsigned short Bh[BN * 40], Bl[BN * 40];
  int z = blockIdx.z, b = z >> 3, h = z & 7;
  const float* Sb = scores + (long long)b * SQ * SQ;
  const unsigned short* Vh = VhT + (long long)b * EE * SQ;
  const unsigned short* Vl = VlT + (long long)b * EE * SQ;
  unsigned short* Chb = Ch + (long long)b * SQ * (NH * EE) + h * EE;
  unsigned short* Clb = Cl + (long long)b * SQ * (NH * EE) + h * EE;
  const float* dz = dist + (long long)z * SQ;
  int m0 = blockIdx.y * 64, n0 = blockIdx.x * BN;
  int tid = threadIdx.x;
  int wave = tid >> 6, lane = tid & 63;
  int quad = lane >> 4, l16 = lane & 15;
  int colb0 = wave * 64;
  f32x4 acc[4][NF];
#pragma unroll
  for (int mf = 0; mf < 4; mf++)
#pragma unroll
    for (int nf = 0; nf < NF; nf++) acc[mf][nf] = (f32x4)(0.f);

  int aam = tid & 63, aakc = tid >> 6;
  float di = dz[m0 + aam];
  float inv = invrs[(long long)z * SQ + m0 + aam];
  const float* Srow = Sb + (long long)(m0 + aam) * SQ;
  int brow = tid;
  const unsigned short* VhRow = Vh + (long long)(n0 + brow) * SQ;
  const unsigned short* VlRow = Vl + (long long)(n0 + brow) * SQ;

  u16x4 aH[2], aL[2];
  u16x8 bH[4], bL[4];

  auto loadconv = [&](int kb) {
#pragma unroll
    for (int r = 0; r < 2; r++) {
      int kc = aakc + r * 4;
      float4 s4 = *(const float4*)(Srow + kb + kc * 4);
      float4 d4 = *(const float4*)(dz + kb + kc * 4);
      float4 a;
      a.x = (s4.x * __builtin_amdgcn_rcpf(1.f + __expf(d4.x - di))) * inv;
      a.y = (s4.y * __builtin_amdgcn_rcpf(1.f + __expf(d4.y - di))) * inv;
      a.z = (s4.z * __builtin_amdgcn_rcpf(1.f + __expf(d4.z - di))) * inv;
      a.w = (s4.w * __builtin_amdgcn_rcpf(1.f + __expf(d4.w - di))) * inv;
      split4(a, aH[r], aL[r]);
    }
#pragma unroll
    for (int c = 0; c < 4; c++) {
      bH[c] = *(const u16x8*)(VhRow + kb + c * 8);
      bL[c] = *(const u16x8*)(VlRow + kb + c * 8);
    }
  };

  loadconv(0);
  for (int k0 = 0; k0 < SQ; k0 += 32) {
    __syncthreads();
#pragma unroll
    for (int r = 0; r < 2; r++) {
      *(u16x4*)&Ah[swzi(aam, aakc + r * 4)] = aH[r];
      *(u16x4*)&Al[swzi(aam, aakc + r * 4)] = aL[r];
    }
#pragma unroll
    for (int c = 0; c < 4; c++) {
      *(u16x8*)&Bh[swzi(brow, 2 * c)] = bH[c];
      *(u16x8*)&Bl[swzi(brow, 2 * c)] = bL[c];
    }
    __syncthreads();
    int kn = (k0 + 32 < SQ) ? (k0 + 32) : k0;  // clamped dummy reload
    loadconv(kn);
    bfrag bhf[NF], blf[NF];
#pragma unroll
    for (int nf = 0; nf < NF; nf++) {
      bhf[nf] = *(const bfrag*)&Bh[swzi(colb0 + nf * 16 + l16, quad * 2)];
      blf[nf] = *(const bfrag*)&Bl[swzi(colb0 + nf * 16 + l16, quad * 2)];
    }
#pragma unroll
    for (int mf = 0; mf < 4; mf++) {
      bfrag ah = *(const bfrag*)&Ah[swzi(mf * 16 + l16, quad * 2)];
      bfrag al = *(const bfrag*)&Al[swzi(mf * 16 + l16, quad * 2)];
#pragma unroll
      for (int nf = 0; nf < NF; nf++) {
        acc[mf][nf] = __builtin_amdgcn_mfma_f32_16x16x32_bf16(al, bhf[nf], acc[mf][nf], 0, 0, 0);
        acc[mf][nf] = __builtin_amdgcn_mfma_f32_16x16x32_bf16(ah, blf[nf], acc[mf][nf], 0, 0, 0);
        acc[mf][nf] = __builtin_amdgcn_mfma_f32_16x16x32_bf16(ah, bhf[nf], acc[mf][nf], 0, 0, 0);
      }
    }
  }
#pragma unroll
  for (int mf = 0; mf < 4; mf++) {
#pragma unroll
    for (int nf = 0; nf < NF; nf++) {
      int col = n0 + colb0 + nf * 16 + l16;
#pragma unroll
      for (int r = 0; r < 4; r++) {
        int row = m0 + mf * 16 + quad * 4 + r;
        float o = acc[mf][nf][r];
        unsigned short hh = f2bf(o);
        Chb[(long long)row * (NH * EE) + col] = hh;
        Clb[(long long)row * (NH * EE) + col] = f2bf(o - bf2f(hh));
      }
    }
  }
}

// ================= bf16x3 MFMA NT-GEMM, pre-split operands, DMA-staged =================
// A/B given as bf16 hi/lo u16 arrays (row-major [rows][K]). Staging via
// global_load_lds (width 16), triple-buffered LDS, prefetch distance 2,
// counted vmcnt(8) + raw s_barrier (never drains the DMA queue in-loop).
// Source-side 2-bit chunk XOR swizzle (s(row)=(row>>1)&3): linear DMA dest,
// swizzled global src + swizzled ds_read -> 2-way (free) LDS reads.
// MFMA stream is BIT-IDENTICAL to the previous gemm_bf3 (same fragments,
// same 3-term order, same K order). OUTM=0: fp32 C (+Res); OUTM=1: split C.
template <int ACT, int OUTM>
__global__ __launch_bounds__(256) void gemm_bf3s(
    const unsigned short* __restrict__ Ah_g, const unsigned short* __restrict__ Al_g, int lda,
    const unsigned short* __restrict__ Bh_g, const unsigned short* __restrict__ Bl_g, int ldb,
    const float* __restrict__ bias, const float* __restrict__ Res,
    float* __restrict__ C, unsigned short* __restrict__ Ch, unsigned short* __restrict__ Cl,
    int ldc, int K) {
  __shared__ __align__(16) unsigned short lds[3][4][64 * 32];  // 48 KB
  // XCD-aware block swizzle: consecutive-8 groups (sharing an A panel) -> one XCD.
  int gx = gridDim.x;
  int nwg = gx * (int)gridDim.y;  // always % 8 == 0 in our launches
  int lin = blockIdx.y * gx + blockIdx.x;
  int cpx = nwg >> 3;
  int tl = (lin & 7) * cpx + (lin >> 3);
  int bx = tl % gx, by = tl / gx;
  int m0 = by * 64, n0 = bx * 64;
  int tid = threadIdx.x, wave = tid >> 6, lane = tid & 63;
  int quad = lane >> 4, l16 = lane & 15;
  int colb0 = wave * 16;

  // staging: wave w owns tile w: 0:Ah 1:Al 2:Bh 3:Bl; 4 quarters each.
  const unsigned short* gsrc = (wave == 0) ? Ah_g : (wave == 1) ? Al_g : (wave == 2) ? Bh_g : Bl_g;
  int gld = (wave < 2) ? lda : ldb;
  int grow0 = (wave < 2) ? m0 : n0;
  long long gbase[4];
#pragma unroll
  for (int qt = 0; qt < 4; qt++) {
    int row = qt * 16 + (lane >> 2);
    int cG = (lane & 3) ^ ((row >> 1) & 3);
    gbase[qt] = (long long)(grow0 + row) * gld + cG * 8;
  }

  auto stage = [&](int buf, int kb) {
#pragma unroll
    for (int qt = 0; qt < 4; qt++) {
      const unsigned short* gp = gsrc + gbase[qt] + kb;
      unsigned short* lp = &lds[buf][wave][qt * 512];
      __builtin_amdgcn_global_load_lds((glb_u32*)gp, (lds_u32*)lp, 16, 0, 0);
    }
  };

  // per-lane swizzled LDS read offsets (u16 indices)
  int aoff[4], boff;
#pragma unroll
  for (int mf = 0; mf < 4; mf++) {
    int r = mf * 16 + l16;
    aoff[mf] = r * 32 + ((quad ^ ((r >> 1) & 3)) * 8);
  }
  {
    int r = colb0 + l16;
    boff = r * 32 + ((quad ^ ((r >> 1) & 3)) * 8);
  }

  f32x4 acc[4];
#pragma unroll
  for (int mf = 0; mf < 4; mf++) acc[mf] = (f32x4)(0.f);

  int NT = K >> 5;
  stage(0, 0);
  stage(1, 32);
  int cur = 0;
  for (int t = 0; t < NT; t++) {
    int nb = cur + 2; if (nb >= 3) nb -= 3;
    int kf = (t + 2 < NT) ? (t + 2) * 32 : (NT - 1) * 32;  // tail: dummy (unread buffer)
    stage(nb, kf);
    asm volatile("s_waitcnt vmcnt(8)" ::: "memory");  // own tile-t DMAs retired
    __builtin_amdgcn_s_barrier();                     // all tiles t resident
    __builtin_amdgcn_sched_barrier(0);
    const unsigned short* Lah = lds[cur][0];
    const unsigned short* Lal = lds[cur][1];
    const unsigned short* Lbh = lds[cur][2];
    const unsigned short* Lbl = lds[cur][3];
    bfrag bh = *(const bfrag*)&Lbh[boff];
    bfrag bl = *(const bfrag*)&Lbl[boff];
#pragma unroll
    for (int mf = 0; mf < 4; mf++) {
      bfrag ah = *(const bfrag*)&Lah[aoff[mf]];
      bfrag al = *(const bfrag*)&Lal[aoff[mf]];
      acc[mf] = __builtin_amdgcn_mfma_f32_16x16x32_bf16(al, bh, acc[mf], 0, 0, 0);
      acc[mf] = __builtin_amdgcn_mfma_f32_16x16x32_bf16(ah, bl, acc[mf], 0, 0, 0);
      acc[mf] = __builtin_amdgcn_mfma_f32_16x16x32_bf16(ah, bh, acc[mf], 0, 0, 0);
    }
    __builtin_amdgcn_sched_barrier(0);
    __builtin_amdgcn_s_barrier();  // all waves done reading buf[cur] before overwrite
    cur++; if (cur >= 3) cur -= 3;
  }

  // epilogue: C/D layout row = quad*4 + r, col = l16
  int col = n0 + colb0 + l16;
  float bi = bias ? bias[col] : 0.f;
#pragma unroll
  for (int mf = 0; mf < 4; mf++) {
#pragma unroll
    for (int r = 0; r < 4; r++) {
      int row = m0 + mf * 16 + quad * 4 + r;
      float o = acc[mf][r] + bi;
      if (ACT == 1) o = gelu_exact(o);
      if (OUTM == 0) {
        if (Res) o = o + Res[(long long)row * ldc + col];
        C[(long long)row * ldc + col] = o;
      } else {
        unsigned short hh = f2bf(o);
        Ch[(long long)row * ldc + col] = hh;
        Cl[(long long)row * ldc + col] = f2bf(o - bf2f(hh));
      }
    }
  }
}

extern "C" void kernel_launch(void* const* d_in, const int* in_sizes, int n_in,
                              void* d_out, int out_size, void* d_ws, size_t ws_size,
                              hipStream_t stream) {
  const float* query     = (const float*)d_in[0];
  const float* ln1_g     = (const float*)d_in[1];
  const float* ln1_b     = (const float*)d_in[2];
  const float* in_proj_w = (const float*)d_in[3];
  const float* in_proj_b = (const float*)d_in[4];
  const float* out_w     = (const float*)d_in[5];
  const float* out_b     = (const float*)d_in[6];
  const float* conv_w    = (const float*)d_in[7];
  const float* conv_b    = (const float*)d_in[8];
  const float* ln2_g     = (const float*)d_in[9];
  const float* ln2_b     = (const float*)d_in[10];
  const float* mlp_w1    = (const float*)d_in[11];
  const float* mlp_b1    = (const float*)d_in[12];
  const float* mlp_w2    = (const float*)d_in[13];
  const float* mlp_b2    = (const float*)d_in[14];
  float* out = (float*)d_out;
  char* ws = (char*)d_ws;

  // Workspace (peak 112.25 MiB, proven safe). Lifetime-disjoint reuse:
  float* nq     = (float*)(ws + 0);                      // [0,8)   dead after step 4
  float* qkv    = (float*)(ws + (8ull << 20));           // [8,32)  dead after step 4 (V via VhT/VlT)
  float* dist   = (float*)(ws + (32ull << 20));          // 128 KiB
  float* invrs  = (float*)(ws + (32ull << 20) + 131072); // 128 KiB
  float* scores = (float*)(ws + (32ull << 20) + 262144); // [32.25,48.25) dead after step 6
  unsigned short* VhT = (unsigned short*)(ws + 0);             // over nq, 4 MiB
  unsigned short* VlT = (unsigned short*)(ws + (4ull << 20));  // 4 MiB
  // ctx pre-split: [48.25,112.25)
  unsigned short* ctxh = (unsigned short*)(ws + (48ull << 20) + 262144);  // 32 MiB
  unsigned short* ctxl = (unsigned short*)(ws + (80ull << 20) + 262144);  // 32 MiB
  // weight splits in dead scores region (written after step 6):
  unsigned short* out_wh = (unsigned short*)(ws + (32ull << 20) + 262144);  // 4 MiB
  unsigned short* out_wl = out_wh + 2097152;                                // 4 MiB
  unsigned short* w1h    = out_wl + 2097152;                                // 2 MiB
  unsigned short* w1l    = w1h + 1048576;                                   // 2 MiB
  unsigned short* w2h    = w1l + 1048576;                                   // 2 MiB
  unsigned short* w2l    = w2h + 1048576;                                   // 2 MiB (ends at 48.25)
  // LN2 split over dead ctxh (after step 7):
  unsigned short* ln2h = (unsigned short*)(ws + (48ull << 20) + 262144);  // 4 MiB
  unsigned short* ln2l = ln2h + 2097152;                                  // 4 MiB
  // MLP hidden split over dead nq+qkv (after step 4):
  unsigned short* hbufh = (unsigned short*)(ws + 0);        // 16 MiB
  unsigned short* hbufl = hbufh + 8388608;                  // 16 MiB (ends at 32)

  // 1. LN1 (frozen)
  ln_np<<<dim3(NB * SQ), 64, 0, stream>>>(query, ln1_g, ln1_b, nq);
  // 2. distances (frozen)
  dist_np<<<dim3(NB * NH, 4), 256, 0, stream>>>(nq, conv_w, conv_b, dist);
  // 3. qkv (frozen chain)  M=4096 N=1536 K=512
  gemm_nt<0, 384><<<dim3(24, 64, 1), 256, 0, stream>>>(nq, EE, 0, in_proj_w, EE, 0,
                                                       in_proj_b, nullptr, qkv, 3 * EE, 0, EE, 1.f);
  // 3b. V transpose + bf16 hi/lo split
  vsplit_t<<<dim3(16, 8, NB), 256, 0, stream>>>(qkv, VhT, VlT);
  // 4. scores (frozen chain + true division)  M=N=1024 K=512, batched B
  gemm_nt<2, 384><<<dim3(16, 16, NB), 256, 0, stream>>>(
      qkv, 3 * EE, (long long)SQ * 3 * EE, qkv + EE, 3 * EE, (long long)SQ * 3 * EE,
      nullptr, nullptr, scores, SQ, (long long)SQ * SQ, EE, sqrtf(512.0f));
  // 5. gated row sums (frozen)
  rowsum_np<<<dim3(SQ, NB * NH), 64, 0, stream>>>(scores, dist, invrs);
  // 6. ctx via bf16x3 MFMA, split output  M=1024 N=512 K=1024, z = B*H
  ctx_bf3<<<dim3(EE / 256, 16, NB * NH), 256, 0, stream>>>(scores, dist, invrs, VhT, VlT,
                                                           ctxh, ctxl);
  // 6b. weight splits (scores region is dead now)
  wsplit<<<dim3(2048), 256, 0, stream>>>(out_w, out_wh, out_wl, 524288);
  wsplit<<<dim3(1024), 256, 0, stream>>>(mlp_w1, w1h, w1l, 262144);
  wsplit<<<dim3(1024), 256, 0, stream>>>(mlp_w2, w2h, w2l, 262144);
  // 7. attn_out + residual (DMA bf16x3)  M=4096 N=512 K=4096
  gemm_bf3s<0, 0><<<dim3(8, 64), 256, 0, stream>>>(ctxh, ctxl, NH * EE, out_wh, out_wl, NH * EE,
                                                   out_b, query, out, nullptr, nullptr,
                                                   EE, NH * EE);
  // 8. LN2, split output
  ln_np_s<<<dim3(NB * SQ), 64, 0, stream>>>(out, ln2_g, ln2_b, ln2h, ln2l);
  // 9. MLP1 + gelu, split output (DMA bf16x3)  M=4096 N=2048 K=512
  gemm_bf3s<1, 1><<<dim3(32, 64), 256, 0, stream>>>(ln2h, ln2l, EE, w1h, w1l, EE,
                                                    mlp_b1, nullptr, nullptr, hbufh, hbufl,
                                                    4 * EE, EE);
  // 10. MLP2 + residual (DMA bf16x3)  M=4096 N=512 K=2048
  gemm_bf3s<0, 0><<<dim3(8, 64), 256, 0, stream>>>(hbufh, hbufl, 4 * EE, w2h, w2l, 4 * EE,
                                                   mlp_b2, out, out, nullptr, nullptr,
                                                   EE, 4 * EE);
}

// Round 4
// 730.082 us; speedup vs baseline: 1.7580x; 1.0255x over previous
//
#include <hip/hip_runtime.h>
#include <math.h>

#define SQ 1024  // S
#define EE 512   // E
#define NB 4     // B
#define NH 8     // H

typedef __attribute__((ext_vector_type(8))) short bfrag;       // 8 bf16 (4 VGPRs)
typedef __attribute__((ext_vector_type(4))) float f32x4;       // MFMA C/D
typedef __attribute__((ext_vector_type(4))) unsigned short u16x4;
typedef __attribute__((ext_vector_type(8))) unsigned short u16x8;

typedef __attribute__((address_space(3))) unsigned int lds_u32;
typedef const __attribute__((address_space(1))) unsigned int glb_u32;

// Optimization barrier: forces materialization (rounding) so the compiler
// cannot FMA-contract or reassociate across numpy's op boundaries.
__device__ __forceinline__ float sep(float x) {
  asm volatile("" : "+v"(x));
  return x;
}

__device__ __forceinline__ unsigned short f2bf(float f) {
  unsigned u = __builtin_bit_cast(unsigned, f);
  unsigned r = (u + 0x7fffu + ((u >> 16) & 1u)) >> 16;
  return (unsigned short)r;
}
__device__ __forceinline__ float bf2f(unsigned short h) {
  unsigned u = ((unsigned)h) << 16;
  return __builtin_bit_cast(float, u);
}

__device__ __forceinline__ void split4(float4 v, u16x4& h, u16x4& l) {
  h.x = f2bf(v.x); l.x = f2bf(v.x - bf2f(h.x));
  h.y = f2bf(v.y); l.y = f2bf(v.y - bf2f(h.y));
  h.z = f2bf(v.z); l.z = f2bf(v.z - bf2f(h.z));
  h.w = f2bf(v.w); l.w = f2bf(v.w - bf2f(h.w));
}

// LDS XOR swizzle for ctx_bf3's reg-staged tiles (row stride 40 u16).
__device__ __forceinline__ int swzi(int row, int c8) {
  return row * 40 + ((c8 ^ ((row >> 2) & 6)) << 2);  // u16 index
}

// ================= LayerNorm, numpy-exact fp32 (np.mean pairwise) — FROZEN =================
__global__ __launch_bounds__(64) void ln_np(const float* __restrict__ x,
                                            const float* __restrict__ g,
                                            const float* __restrict__ b,
                                            float* __restrict__ y) {
  __shared__ float xs[EE];
  __shared__ float bc[2];
  long long t = blockIdx.x;
  int lane = threadIdx.x;
#pragma unroll
  for (int m = 0; m < 8; m++) xs[lane + 64 * m] = x[t * EE + lane + 64 * m];
  __syncthreads();
  int l = lane >> 3, a = lane & 7;
  float r = 0.f;
  if (lane < 32) {
    r = xs[l * 128 + a];
#pragma unroll
    for (int m = 1; m < 16; m++) r = r + xs[l * 128 + 8 * m + a];
  }
  r = r + __shfl_xor(r, 1);
  r = r + __shfl_xor(r, 2);
  r = r + __shfl_xor(r, 4);
  r = r + __shfl_xor(r, 8);
  r = r + __shfl_xor(r, 16);
  if (lane == 0) bc[0] = r / 512.0f;
  __syncthreads();
  float mean = bc[0];
  r = 0.f;
  if (lane < 32) {
#pragma unroll
    for (int m = 0; m < 16; m++) {
      float d = sep(xs[l * 128 + 8 * m + a] - mean);
      float s2 = sep(d * d);
      r = (m == 0) ? s2 : (r + s2);
    }
  }
  r = r + __shfl_xor(r, 1);
  r = r + __shfl_xor(r, 2);
  r = r + __shfl_xor(r, 4);
  r = r + __shfl_xor(r, 8);
  r = r + __shfl_xor(r, 16);
  if (lane == 0) bc[1] = r / 512.0f;
  __syncthreads();
  float var = bc[1];
  float rs = 1.0f / sqrtf(var + 1e-5f);
#pragma unroll
  for (int m = 0; m < 8; m++) {
    int i = lane + 64 * m;
    float d = sep(xs[i] - mean);
    float t1 = sep(d * rs);
    float t2 = sep(t1 * g[i]);
    y[t * EE + i] = t2 + b[i];
  }
}

// ===== LayerNorm with split bf16 hi/lo output (same frozen math, split store) =====
__global__ __launch_bounds__(64) void ln_np_s(const float* __restrict__ x,
                                              const float* __restrict__ g,
                                              const float* __restrict__ b,
                                              unsigned short* __restrict__ yh,
                                              unsigned short* __restrict__ yl) {
  __shared__ float xs[EE];
  __shared__ float bc[2];
  long long t = blockIdx.x;
  int lane = threadIdx.x;
#pragma unroll
  for (int m = 0; m < 8; m++) xs[lane + 64 * m] = x[t * EE + lane + 64 * m];
  __syncthreads();
  int l = lane >> 3, a = lane & 7;
  float r = 0.f;
  if (lane < 32) {
    r = xs[l * 128 + a];
#pragma unroll
    for (int m = 1; m < 16; m++) r = r + xs[l * 128 + 8 * m + a];
  }
  r = r + __shfl_xor(r, 1);
  r = r + __shfl_xor(r, 2);
  r = r + __shfl_xor(r, 4);
  r = r + __shfl_xor(r, 8);
  r = r + __shfl_xor(r, 16);
  if (lane == 0) bc[0] = r / 512.0f;
  __syncthreads();
  float mean = bc[0];
  r = 0.f;
  if (lane < 32) {
#pragma unroll
    for (int m = 0; m < 16; m++) {
      float d = sep(xs[l * 128 + 8 * m + a] - mean);
      float s2 = sep(d * d);
      r = (m == 0) ? s2 : (r + s2);
    }
  }
  r = r + __shfl_xor(r, 1);
  r = r + __shfl_xor(r, 2);
  r = r + __shfl_xor(r, 4);
  r = r + __shfl_xor(r, 8);
  r = r + __shfl_xor(r, 16);
  if (lane == 0) bc[1] = r / 512.0f;
  __syncthreads();
  float var = bc[1];
  float rs = 1.0f / sqrtf(var + 1e-5f);
#pragma unroll
  for (int m = 0; m < 8; m++) {
    int i = lane + 64 * m;
    float d = sep(xs[i] - mean);
    float t1 = sep(d * rs);
    float t2 = sep(t1 * g[i]);
    float o = t2 + b[i];
    unsigned short hh = f2bf(o);
    yh[t * EE + i] = hh;
    yl[t * EE + i] = f2bf(o - bf2f(hh));
  }
}

// ================= distances — FROZEN math; s-range split over blockIdx.y =================
__global__ __launch_bounds__(256) void dist_np(const float* __restrict__ nq,
                                               const float* __restrict__ conv_w,
                                               const float* __restrict__ conv_b,
                                               float* __restrict__ dist) {
  int bh = blockIdx.x;
  int b = bh >> 3, h = bh & 7;
  float cb = conv_b[h];
  const float* W = conv_w + (long long)h * EE * 3;
  int s = blockIdx.y * 256 + threadIdx.x;
  float d = cb;
#pragma unroll
  for (int k = 0; k < 3; k++) {
    int t = s - 2 + k;
    if (t < 0) continue;
    const float* row = nq + ((long long)b * SQ + t) * EE;
    float acc = 0.f;
    for (int e = 0; e < EE; e++) acc = __builtin_fmaf(row[e], W[e * 3 + k], acc);
    d = sep(d + acc);
  }
  dist[(long long)bh * SQ + s] = (float)tanh((double)d);
}

// ================= fp32 tiled NT-GEMM — FROZEN DAG (R12, byte-identical) =================
__device__ __forceinline__ float gelu_exact(float x) {
  return 0.5f * x * (1.f + erff(x / 1.41421356237309504880f));
}

template <int ACT, int SPLITK>
__global__ __launch_bounds__(256) void gemm_nt(const float* __restrict__ A, int lda, long long sA,
                                               const float* __restrict__ B, int ldb, long long sB,
                                               const float* __restrict__ bias,
                                               const float* __restrict__ Res,
                                               float* __restrict__ C, int ldc, long long sC,
                                               int K, float alpha) {
  __shared__ float As[16][68];
  __shared__ float Bs[16][68];
  int z = blockIdx.z;
  A += (long long)z * sA;
  B += (long long)z * sB;
  C += (long long)z * sC;
  int m0 = blockIdx.y * 64, n0 = blockIdx.x * 64;
  int tid = threadIdx.x;
  int lr = tid >> 2, lc = tid & 3;
  int tx = tid & 15, ty = tid >> 4;
  float acc[4][4] = {};
  float acc2[4][4] = {};
  const float* Arow = A + (long long)(m0 + lr) * lda + lc * 4;
  const float* Brow = B + (long long)(n0 + lr) * ldb + lc * 4;
  float4 a4 = *(const float4*)(Arow);
  float4 b4 = *(const float4*)(Brow);
  for (int k0 = 0; k0 < K; k0 += 16) {
    __syncthreads();
    As[lc * 4 + 0][lr] = a4.x; As[lc * 4 + 1][lr] = a4.y;
    As[lc * 4 + 2][lr] = a4.z; As[lc * 4 + 3][lr] = a4.w;
    Bs[lc * 4 + 0][lr] = b4.x; Bs[lc * 4 + 1][lr] = b4.y;
    Bs[lc * 4 + 2][lr] = b4.z; Bs[lc * 4 + 3][lr] = b4.w;
    __syncthreads();
    int kn = (k0 + 16 < K) ? (k0 + 16) : k0;
    float4 a4n = *(const float4*)(Arow + kn);
    float4 b4n = *(const float4*)(Brow + kn);
    float(*tgt)[4] = (SPLITK > 0 && k0 >= SPLITK) ? acc2 : acc;
#pragma unroll
    for (int kk = 0; kk < 16; kk++) {
      float4 av = *(const float4*)&As[kk][ty * 4];
      float4 bv = *(const float4*)&Bs[kk][tx * 4];
      float a[4] = {av.x, av.y, av.z, av.w};
      float bb[4] = {bv.x, bv.y, bv.z, bv.w};
#pragma unroll
      for (int i = 0; i < 4; i++)
#pragma unroll
        for (int j = 0; j < 4; j++) tgt[i][j] += a[i] * bb[j];
    }
    a4 = a4n;
    b4 = b4n;
  }
  if (SPLITK > 0) {
#pragma unroll
    for (int i = 0; i < 4; i++)
#pragma unroll
      for (int j = 0; j < 4; j++) acc[i][j] = sep(acc[i][j]) + acc2[i][j];
  }
  float4 bias4 = make_float4(0.f, 0.f, 0.f, 0.f);
  if (ACT != 2 && bias) bias4 = *(const float4*)(bias + n0 + tx * 4);
#pragma unroll
  for (int i = 0; i < 4; i++) {
    int row = m0 + ty * 4 + i;
    float o[4];
    if (ACT == 2) {
#pragma unroll
      for (int j = 0; j < 4; j++) o[j] = acc[i][j] / alpha;
    } else {
      o[0] = sep(acc[i][0] * alpha) + bias4.x;
      o[1] = sep(acc[i][1] * alpha) + bias4.y;
      o[2] = sep(acc[i][2] * alpha) + bias4.z;
      o[3] = sep(acc[i][3] * alpha) + bias4.w;
    }
    if (ACT == 1) {
#pragma unroll
      for (int j = 0; j < 4; j++) o[j] = gelu_exact(o[j]);
    }
    if (Res) {
      float4 r4 = *(const float4*)(Res + (long long)row * ldc + n0 + tx * 4);
      o[0] = sep(o[0]) + r4.x; o[1] = sep(o[1]) + r4.y;
      o[2] = sep(o[2]) + r4.z; o[3] = sep(o[3]) + r4.w;
    }
    *(float4*)(C + (long long)row * ldc + n0 + tx * 4) = make_float4(o[0], o[1], o[2], o[3]);
  }
}

// ================= gated row sums: np.sum pairwise(1024) — FROZEN =================
__global__ __launch_bounds__(64) void rowsum_np(const float* __restrict__ scores,
                                                const float* __restrict__ dist,
                                                float* __restrict__ invrs) {
  __shared__ float wsm[SQ];
  int i = blockIdx.x;
  int z = blockIdx.y;
  int b = z >> 3;
  const float* srow = scores + ((long long)b * SQ + i) * SQ;
  const float* dz = dist + (long long)z * SQ;
  float di = dz[i];
  int lane = threadIdx.x;
#pragma unroll
  for (int m = 0; m < 16; m++) {
    int j = lane + 64 * m;
    float e = (float)exp((double)(dz[j] - di));
    float gg = 1.f / (1.f + e);
    wsm[j] = srow[j] * gg;
  }
  __syncthreads();
  int l = lane >> 3, a = lane & 7;
  float r = wsm[l * 128 + a];
#pragma unroll
  for (int m = 1; m < 16; m++) r = r + wsm[l * 128 + 8 * m + a];
  r = r + __shfl_xor(r, 1);
  r = r + __shfl_xor(r, 2);
  r = r + __shfl_xor(r, 4);
  r = r + __shfl_xor(r, 8);
  r = r + __shfl_xor(r, 16);
  r = r + __shfl_xor(r, 32);
  if (lane == 0) invrs[(long long)z * SQ + i] = 1.f / (r + 1e-12f);
}

// ================= V transpose + bf16 hi/lo split:  VhT/VlT[b][e][j] = split(V[b][j][e]) =================
__global__ __launch_bounds__(256) void vsplit_t(const float* __restrict__ qkv,
                                                unsigned short* __restrict__ VhT,
                                                unsigned short* __restrict__ VlT) {
  __shared__ float tile[64][65];
  int b = blockIdx.z;
  int j0 = blockIdx.x * 64;  // S tile
  int e0 = blockIdx.y * 64;  // E tile
  const float* V = qkv + (long long)b * SQ * (3 * EE) + 2 * EE;
  unsigned short* Vh = VhT + (long long)b * EE * SQ;
  unsigned short* Vl = VlT + (long long)b * EE * SQ;
  int tx = threadIdx.x & 15, ty = threadIdx.x >> 4;
#pragma unroll
  for (int r = 0; r < 4; r++) {
    int j = j0 + ty + r * 16;
    float4 v = *(const float4*)(V + (long long)j * (3 * EE) + e0 + tx * 4);
    tile[ty + r * 16][tx * 4 + 0] = v.x;
    tile[ty + r * 16][tx * 4 + 1] = v.y;
    tile[ty + r * 16][tx * 4 + 2] = v.z;
    tile[ty + r * 16][tx * 4 + 3] = v.w;
  }
  __syncthreads();
#pragma unroll
  for (int r = 0; r < 4; r++) {
    int el = ty + r * 16;
    float4 f;
    f.x = tile[tx * 4 + 0][el];
    f.y = tile[tx * 4 + 1][el];
    f.z = tile[tx * 4 + 2][el];
    f.w = tile[tx * 4 + 3][el];
    u16x4 hh, ll;
    split4(f, hh, ll);
    long long o = (long long)(e0 + el) * SQ + j0 + tx * 4;
    *(u16x4*)(Vh + o) = hh;
    *(u16x4*)(Vl + o) = ll;
  }
}

// ===== flat fp32 -> bf16 hi/lo split (weights); n4 = count/4 =====
__global__ __launch_bounds__(256) void wsplit(const float* __restrict__ W,
                                              unsigned short* __restrict__ Wh,
                                              unsigned short* __restrict__ Wl, int n4) {
  int i = blockIdx.x * 256 + threadIdx.x;
  if (i >= n4) return;
  float4 v = *(const float4*)(W + (long long)i * 4);
  u16x4 h, l;
  split4(v, h, l);
  *(u16x4*)(Wh + (long long)i * 4) = h;
  *(u16x4*)(Wl + (long long)i * 4) = l;
}

// ================= ctx GEMM via bf16x3 MFMA — BM=128 x BN=128, fast gate, swizzled LDS =================
// ctx[b,h,i,e] = sum_j ((scores[i,j]*sigmoid_fast(di-dj))*inv_i) * V[j,e]
// Same gate math / per-element accumulation chain as the round-3 version
// (bit-identical outputs); re-tiled for occupancy: 40 KiB LDS, 4 waves each
// owning a 64x64 sub-tile (4x4 frags), ~12 waves/CU resident.
__global__ __launch_bounds__(256) void ctx_bf3(const float* __restrict__ scores,
                                               const float* __restrict__ dist,
                                               const float* __restrict__ invrs,
                                               const unsigned short* __restrict__ VhT,
                                               const unsigned short* __restrict__ VlT,
                                               unsigned short* __restrict__ Ch,
                                               unsigned short* __restrict__ Cl) {
  __shared__ __align__(16) unsigned short Ah[128 * 40], Al[128 * 40];
  __shared__ __align__(16) unsigned short Bh[128 * 40], Bl[128 * 40];
  int z = blockIdx.z, b = z >> 3, h = z & 7;
  const float* Sb = scores + (long long)b * SQ * SQ;
  const unsigned short* Vh = VhT + (long long)b * EE * SQ;
  const unsigned short* Vl = VlT + (long long)b * EE * SQ;
  unsigned short* Chb = Ch + (long long)b * SQ * (NH * EE) + h * EE;
  unsigned short* Clb = Cl + (long long)b * SQ * (NH * EE) + h * EE;
  const float* dz = dist + (long long)z * SQ;
  int m0 = blockIdx.y * 128, n0 = blockIdx.x * 128;
  int tid = threadIdx.x;
  int wave = tid >> 6, lane = tid & 63;
  int quad = lane >> 4, l16 = lane & 15;
  f32x4 acc[4][4];
#pragma unroll
  for (int mf = 0; mf < 4; mf++)
#pragma unroll
    for (int nf = 0; nf < 4; nf++) acc[mf][nf] = (f32x4)(0.f);

  // A staging: 2 threads per row; thread covers k-chunks (aakc*4 + r)*4, r=0..3
  int aam = tid & 127, aakc = tid >> 7;
  float di = dz[m0 + aam];
  float inv = invrs[(long long)z * SQ + m0 + aam];
  const float* Srow = Sb + (long long)(m0 + aam) * SQ;
  // B staging: 2 threads per row; thread covers 2 u16x8 chunks
  int brow = tid & 127, bk8 = tid >> 7;
  const unsigned short* VhRow = Vh + (long long)(n0 + brow) * SQ;
  const unsigned short* VlRow = Vl + (long long)(n0 + brow) * SQ;

  u16x4 aH[4], aL[4];
  u16x8 bH[2], bL[2];

  auto loadconv = [&](int kb) {
#pragma unroll
    for (int r = 0; r < 4; r++) {
      int kc = aakc * 4 + r;
      float4 s4 = *(const float4*)(Srow + kb + kc * 4);
      float4 d4 = *(const float4*)(dz + kb + kc * 4);
      float4 a;
      a.x = (s4.x * __builtin_amdgcn_rcpf(1.f + __expf(d4.x - di))) * inv;
      a.y = (s4.y * __builtin_amdgcn_rcpf(1.f + __expf(d4.y - di))) * inv;
      a.z = (s4.z * __builtin_amdgcn_rcpf(1.f + __expf(d4.z - di))) * inv;
      a.w = (s4.w * __builtin_amdgcn_rcpf(1.f + __expf(d4.w - di))) * inv;
      split4(a, aH[r], aL[r]);
    }
#pragma unroll
    for (int r = 0; r < 2; r++) {
      bH[r] = *(const u16x8*)(VhRow + kb + (bk8 * 2 + r) * 8);
      bL[r] = *(const u16x8*)(VlRow + kb + (bk8 * 2 + r) * 8);
    }
  };

  loadconv(0);
  for (int k0 = 0; k0 < SQ; k0 += 32) {
    __syncthreads();
#pragma unroll
    for (int r = 0; r < 4; r++) {
      *(u16x4*)&Ah[swzi(aam, aakc * 4 + r)] = aH[r];
      *(u16x4*)&Al[swzi(aam, aakc * 4 + r)] = aL[r];
    }
#pragma unroll
    for (int r = 0; r < 2; r++) {
      *(u16x8*)&Bh[swzi(brow, (bk8 * 2 + r) * 2)] = bH[r];
      *(u16x8*)&Bl[swzi(brow, (bk8 * 2 + r) * 2)] = bL[r];
    }
    __syncthreads();
    int kn = (k0 + 32 < SQ) ? (k0 + 32) : k0;  // clamped dummy reload
    loadconv(kn);
    bfrag bhf[4], blf[4];
#pragma unroll
    for (int nf = 0; nf < 4; nf++) {
      int rb = (wave & 1) * 64 + nf * 16 + l16;
      bhf[nf] = *(const bfrag*)&Bh[swzi(rb, quad * 2)];
      blf[nf] = *(const bfrag*)&Bl[swzi(rb, quad * 2)];
    }
#pragma unroll
    for (int mf = 0; mf < 4; mf++) {
      int ra = (wave >> 1) * 64 + mf * 16 + l16;
      bfrag ah = *(const bfrag*)&Ah[swzi(ra, quad * 2)];
      bfrag al = *(const bfrag*)&Al[swzi(ra, quad * 2)];
#pragma unroll
      for (int nf = 0; nf < 4; nf++) {
        acc[mf][nf] = __builtin_amdgcn_mfma_f32_16x16x32_bf16(al, bhf[nf], acc[mf][nf], 0, 0, 0);
        acc[mf][nf] = __builtin_amdgcn_mfma_f32_16x16x32_bf16(ah, blf[nf], acc[mf][nf], 0, 0, 0);
        acc[mf][nf] = __builtin_amdgcn_mfma_f32_16x16x32_bf16(ah, bhf[nf], acc[mf][nf], 0, 0, 0);
      }
    }
  }
#pragma unroll
  for (int mf = 0; mf < 4; mf++) {
#pragma unroll
    for (int nf = 0; nf < 4; nf++) {
      int col = n0 + (wave & 1) * 64 + nf * 16 + l16;
#pragma unroll
      for (int r = 0; r < 4; r++) {
        int row = m0 + (wave >> 1) * 64 + mf * 16 + quad * 4 + r;
        float o = acc[mf][nf][r];
        unsigned short hh = f2bf(o);
        Chb[(long long)row * (NH * EE) + col] = hh;
        Clb[(long long)row * (NH * EE) + col] = f2bf(o - bf2f(hh));
      }
    }
  }
}

// ================= bf16x3 MFMA NT-GEMM, pre-split operands, DMA-staged, WIDE =================
// 128x64 block, 4 waves each owning a 64x32 sub-tile (4x2 frags -> 24 MFMA per
// 12 frag-reads: 2x arithmetic intensity vs the 64x64 version). Staging via
// global_load_lds (width 16), triple-buffered LDS (72 KB), prefetch distance 2,
// counted vmcnt(12) (6 DMAs/wave/tile). Source-side 2-bit chunk XOR swizzle;
// per-output-element accumulation chain BIT-IDENTICAL to gemm_bf3s/gemm_bf3.
template <int ACT, int OUTM>
__global__ __launch_bounds__(256) void gemm_bf3w(
    const unsigned short* __restrict__ Ah_g, const unsigned short* __restrict__ Al_g, int lda,
    const unsigned short* __restrict__ Bh_g, const unsigned short* __restrict__ Bl_g, int ldb,
    const float* __restrict__ bias, const float* __restrict__ Res,
    float* __restrict__ C, unsigned short* __restrict__ Ch, unsigned short* __restrict__ Cl,
    int ldc, int K) {
  __shared__ __align__(16) unsigned short lds[3 * 12288];  // 3 bufs x 24 KB
  // XCD-aware block swizzle (nwg % 8 == 0 in all our launches)
  int gx = gridDim.x;
  int nwg = gx * (int)gridDim.y;
  int lin = blockIdx.y * gx + blockIdx.x;
  int cpx = nwg >> 3;
  int tl = (lin & 7) * cpx + (lin >> 3);
  int bx = tl % gx, by = tl / gx;
  int m0 = by * 128, n0 = bx * 64;
  int tid = threadIdx.x, wave = tid >> 6, lane = tid & 63;
  int quad = lane >> 4, l16 = lane & 15;

  // 24 DMA slots per K-tile (Ah:8, Al:8, Bh:4, Bl:4); wave w owns slots w*6..w*6+5
  const unsigned short* gptr[6];
  int ldsoff[6];
#pragma unroll
  for (int i = 0; i < 6; i++) {
    int d = wave * 6 + i;
    const unsigned short* src;
    int rowbase, ld, tb, qt;
    if (d < 8)       { src = Ah_g; rowbase = m0; ld = lda; tb = 0;     qt = d; }
    else if (d < 16) { src = Al_g; rowbase = m0; ld = lda; tb = 4096;  qt = d - 8; }
    else if (d < 20) { src = Bh_g; rowbase = n0; ld = ldb; tb = 8192;  qt = d - 16; }
    else             { src = Bl_g; rowbase = n0; ld = ldb; tb = 10240; qt = d - 20; }
    int row = qt * 16 + (lane >> 2);
    int cG = (lane & 3) ^ ((row >> 1) & 3);
    gptr[i] = src + (long long)(rowbase + row) * ld + cG * 8;
    ldsoff[i] = tb + qt * 512;
  }

  auto stage = [&](int buf, int kb) {
#pragma unroll
    for (int i = 0; i < 6; i++)
      __builtin_amdgcn_global_load_lds((glb_u32*)(gptr[i] + kb),
                                       (lds_u32*)&lds[buf * 12288 + ldsoff[i]], 16, 0, 0);
  };

  // per-lane swizzled LDS read offsets (u16 indices within a buffer)
  int aoff[4], boff[2];
#pragma unroll
  for (int mf = 0; mf < 4; mf++) {
    int r = (wave >> 1) * 64 + mf * 16 + l16;
    aoff[mf] = r * 32 + ((quad ^ ((r >> 1) & 3)) * 8);
  }
#pragma unroll
  for (int nf = 0; nf < 2; nf++) {
    int r = (wave & 1) * 32 + nf * 16 + l16;
    boff[nf] = r * 32 + ((quad ^ ((r >> 1) & 3)) * 8);
  }

  f32x4 acc[4][2];
#pragma unroll
  for (int mf = 0; mf < 4; mf++)
#pragma unroll
    for (int nf = 0; nf < 2; nf++) acc[mf][nf] = (f32x4)(0.f);

  int NT = K >> 5;
  stage(0, 0);
  stage(1, 32);
  int cur = 0;
  for (int t = 0; t < NT; t++) {
    int nb = cur + 2; if (nb >= 3) nb -= 3;
    int kf = (t + 2 < NT) ? (t + 2) * 32 : (NT - 1) * 32;  // tail: dummy (unread buffer)
    stage(nb, kf);
    asm volatile("s_waitcnt vmcnt(12)" ::: "memory");  // own tile-t DMAs retired
    __builtin_amdgcn_s_barrier();                      // all tiles t resident
    __builtin_amdgcn_sched_barrier(0);
    const unsigned short* L = &lds[cur * 12288];
    bfrag bh[2], bl[2];
#pragma unroll
    for (int nf = 0; nf < 2; nf++) {
      bh[nf] = *(const bfrag*)&L[8192 + boff[nf]];
      bl[nf] = *(const bfrag*)&L[10240 + boff[nf]];
    }
#pragma unroll
    for (int mf = 0; mf < 4; mf++) {
      bfrag ah = *(const bfrag*)&L[aoff[mf]];
      bfrag al = *(const bfrag*)&L[4096 + aoff[mf]];
#pragma unroll
      for (int nf = 0; nf < 2; nf++) {
        acc[mf][nf] = __builtin_amdgcn_mfma_f32_16x16x32_bf16(al, bh[nf], acc[mf][nf], 0, 0, 0);
        acc[mf][nf] = __builtin_amdgcn_mfma_f32_16x16x32_bf16(ah, bl[nf], acc[mf][nf], 0, 0, 0);
        acc[mf][nf] = __builtin_amdgcn_mfma_f32_16x16x32_bf16(ah, bh[nf], acc[mf][nf], 0, 0, 0);
      }
    }
    __builtin_amdgcn_sched_barrier(0);
    __builtin_amdgcn_s_barrier();  // all waves done reading buf[cur] before overwrite
    cur++; if (cur >= 3) cur -= 3;
  }

  // epilogue: C/D layout row = quad*4 + r, col = l16
#pragma unroll
  for (int mf = 0; mf < 4; mf++) {
#pragma unroll
    for (int nf = 0; nf < 2; nf++) {
      int col = n0 + (wave & 1) * 32 + nf * 16 + l16;
      float bi = bias ? bias[col] : 0.f;
#pragma unroll
      for (int r = 0; r < 4; r++) {
        int row = m0 + (wave >> 1) * 64 + mf * 16 + quad * 4 + r;
        float o = acc[mf][nf][r] + bi;
        if (ACT == 1) o = gelu_exact(o);
        if (OUTM == 0) {
          if (Res) o = o + Res[(long long)row * ldc + col];
          C[(long long)row * ldc + col] = o;
        } else {
          unsigned short hh = f2bf(o);
          Ch[(long long)row * ldc + col] = hh;
          Cl[(long long)row * ldc + col] = f2bf(o - bf2f(hh));
        }
      }
    }
  }
}

extern "C" void kernel_launch(void* const* d_in, const int* in_sizes, int n_in,
                              void* d_out, int out_size, void* d_ws, size_t ws_size,
                              hipStream_t stream) {
  const float* query     = (const float*)d_in[0];
  const float* ln1_g     = (const float*)d_in[1];
  const float* ln1_b     = (const float*)d_in[2];
  const float* in_proj_w = (const float*)d_in[3];
  const float* in_proj_b = (const float*)d_in[4];
  const float* out_w     = (const float*)d_in[5];
  const float* out_b     = (const float*)d_in[6];
  const float* conv_w    = (const float*)d_in[7];
  const float* conv_b    = (const float*)d_in[8];
  const float* ln2_g     = (const float*)d_in[9];
  const float* ln2_b     = (const float*)d_in[10];
  const float* mlp_w1    = (const float*)d_in[11];
  const float* mlp_b1    = (const float*)d_in[12];
  const float* mlp_w2    = (const float*)d_in[13];
  const float* mlp_b2    = (const float*)d_in[14];
  float* out = (float*)d_out;
  char* ws = (char*)d_ws;

  // Workspace (peak 112.25 MiB, proven safe). Lifetime-disjoint reuse:
  float* nq     = (float*)(ws + 0);                      // [0,8)   dead after step 4
  float* qkv    = (float*)(ws + (8ull << 20));           // [8,32)  dead after step 4 (V via VhT/VlT)
  float* dist   = (float*)(ws + (32ull << 20));          // 128 KiB
  float* invrs  = (float*)(ws + (32ull << 20) + 131072); // 128 KiB
  float* scores = (float*)(ws + (32ull << 20) + 262144); // [32.25,48.25) dead after step 6
  unsigned short* VhT = (unsigned short*)(ws + 0);             // over nq, 4 MiB
  unsigned short* VlT = (unsigned short*)(ws + (4ull << 20));  // 4 MiB
  // ctx pre-split: [48.25,112.25)
  unsigned short* ctxh = (unsigned short*)(ws + (48ull << 20) + 262144);  // 32 MiB
  unsigned short* ctxl = (unsigned short*)(ws + (80ull << 20) + 262144);  // 32 MiB
  // weight splits in dead scores region (written after step 6):
  unsigned short* out_wh = (unsigned short*)(ws + (32ull << 20) + 262144);  // 4 MiB
  unsigned short* out_wl = out_wh + 2097152;                                // 4 MiB
  unsigned short* w1h    = out_wl + 2097152;                                // 2 MiB
  unsigned short* w1l    = w1h + 1048576;                                   // 2 MiB
  unsigned short* w2h    = w1l + 1048576;                                   // 2 MiB
  unsigned short* w2l    = w2h + 1048576;                                   // 2 MiB (ends at 48.25)
  // LN2 split over dead ctxh (after step 7):
  unsigned short* ln2h = (unsigned short*)(ws + (48ull << 20) + 262144);  // 4 MiB
  unsigned short* ln2l = ln2h + 2097152;                                  // 4 MiB
  // MLP hidden split over dead nq+qkv (after step 4):
  unsigned short* hbufh = (unsigned short*)(ws + 0);        // 16 MiB
  unsigned short* hbufl = hbufh + 8388608;                  // 16 MiB (ends at 32)

  // 1. LN1 (frozen)
  ln_np<<<dim3(NB * SQ), 64, 0, stream>>>(query, ln1_g, ln1_b, nq);
  // 2. distances (frozen)
  dist_np<<<dim3(NB * NH, 4), 256, 0, stream>>>(nq, conv_w, conv_b, dist);
  // 3. qkv (frozen chain)  M=4096 N=1536 K=512
  gemm_nt<0, 384><<<dim3(24, 64, 1), 256, 0, stream>>>(nq, EE, 0, in_proj_w, EE, 0,
                                                       in_proj_b, nullptr, qkv, 3 * EE, 0, EE, 1.f);
  // 3b. V transpose + bf16 hi/lo split
  vsplit_t<<<dim3(16, 8, NB), 256, 0, stream>>>(qkv, VhT, VlT);
  // 4. scores (frozen chain + true division)  M=N=1024 K=512, batched B
  gemm_nt<2, 384><<<dim3(16, 16, NB), 256, 0, stream>>>(
      qkv, 3 * EE, (long long)SQ * 3 * EE, qkv + EE, 3 * EE, (long long)SQ * 3 * EE,
      nullptr, nullptr, scores, SQ, (long long)SQ * SQ, EE, sqrtf(512.0f));
  // 5. gated row sums (frozen)
  rowsum_np<<<dim3(SQ, NB * NH), 64, 0, stream>>>(scores, dist, invrs);
  // 6. ctx via bf16x3 MFMA, split output  M=1024 N=512 K=1024, z = B*H, 128x128 tiles
  ctx_bf3<<<dim3(4, 8, NB * NH), 256, 0, stream>>>(scores, dist, invrs, VhT, VlT,
                                                   ctxh, ctxl);
  // 6b. weight splits (scores region is dead now)
  wsplit<<<dim3(2048), 256, 0, stream>>>(out_w, out_wh, out_wl, 524288);
  wsplit<<<dim3(1024), 256, 0, stream>>>(mlp_w1, w1h, w1l, 262144);
  wsplit<<<dim3(1024), 256, 0, stream>>>(mlp_w2, w2h, w2l, 262144);
  // 7. attn_out + residual (wide DMA bf16x3)  M=4096 N=512 K=4096
  gemm_bf3w<0, 0><<<dim3(8, 32), 256, 0, stream>>>(ctxh, ctxl, NH * EE, out_wh, out_wl, NH * EE,
                                                   out_b, query, out, nullptr, nullptr,
                                                   EE, NH * EE);
  // 8. LN2, split output
  ln_np_s<<<dim3(NB * SQ), 64, 0, stream>>>(out, ln2_g, ln2_b, ln2h, ln2l);
  // 9. MLP1 + gelu, split output (wide DMA bf16x3)  M=4096 N=2048 K=512
  gemm_bf3w<1, 1><<<dim3(32, 32), 256, 0, stream>>>(ln2h, ln2l, EE, w1h, w1l, EE,
                                                    mlp_b1, nullptr, nullptr, hbufh, hbufl,
                                                    4 * EE, EE);
  // 10. MLP2 + residual (wide DMA bf16x3)  M=4096 N=512 K=2048
  gemm_bf3w<0, 0><<<dim3(8, 32), 256, 0, stream>>>(hbufh, hbufl, 4 * EE, w2h, w2l, 4 * EE,
                                                   mlp_b2, out, out, nullptr, nullptr,
                                                   EE, 4 * EE);
}

// Round 6
// 669.397 us; speedup vs baseline: 1.9174x; 1.0907x over previous
//
#include <hip/hip_runtime.h>
#include <math.h>

#define SQ 1024  // S
#define EE 512   // E
#define NB 4     // B
#define NH 8     // H

typedef __attribute__((ext_vector_type(8))) short bfrag;       // 8 bf16 (4 VGPRs)
typedef __attribute__((ext_vector_type(4))) float f32x4;       // MFMA C/D
typedef __attribute__((ext_vector_type(4))) unsigned short u16x4;
typedef __attribute__((ext_vector_type(8))) unsigned short u16x8;

typedef __attribute__((address_space(3))) unsigned int lds_u32;
typedef const __attribute__((address_space(1))) unsigned int glb_u32;

// Optimization barrier: forces materialization (rounding) so the compiler
// cannot FMA-contract or reassociate across numpy's op boundaries.
__device__ __forceinline__ float sep(float x) {
  asm volatile("" : "+v"(x));
  return x;
}

__device__ __forceinline__ unsigned short f2bf(float f) {
  unsigned u = __builtin_bit_cast(unsigned, f);
  unsigned r = (u + 0x7fffu + ((u >> 16) & 1u)) >> 16;
  return (unsigned short)r;
}
__device__ __forceinline__ float bf2f(unsigned short h) {
  unsigned u = ((unsigned)h) << 16;
  return __builtin_bit_cast(float, u);
}
__device__ __forceinline__ float bitf(unsigned u) { return __builtin_bit_cast(float, u); }

// packed f32x2 -> bf16x2 (lo16 = bf16(a), hi16 = bf16(b))
__device__ __forceinline__ unsigned cvtpk(float a, float b) {
  unsigned r;
  asm("v_cvt_pk_bf16_f32 %0, %1, %2" : "=v"(r) : "v"(a), "v"(b));
  return r;
}

__device__ __forceinline__ void split4(float4 v, u16x4& h, u16x4& l) {
  h.x = f2bf(v.x); l.x = f2bf(v.x - bf2f(h.x));
  h.y = f2bf(v.y); l.y = f2bf(v.y - bf2f(h.y));
  h.z = f2bf(v.z); l.z = f2bf(v.z - bf2f(h.z));
  h.w = f2bf(v.w); l.w = f2bf(v.w - bf2f(h.w));
}

// LDS XOR swizzle for reg-staged tiles (row stride 40 u16).
__device__ __forceinline__ int swzi(int row, int c8) {
  return row * 40 + ((c8 ^ ((row >> 2) & 6)) << 2);  // u16 index
}

// ================= LayerNorm, numpy-exact fp32 (np.mean pairwise) — FROZEN =================
__global__ __launch_bounds__(64) void ln_np(const float* __restrict__ x,
                                            const float* __restrict__ g,
                                            const float* __restrict__ b,
                                            float* __restrict__ y) {
  __shared__ float xs[EE];
  __shared__ float bc[2];
  long long t = blockIdx.x;
  int lane = threadIdx.x;
#pragma unroll
  for (int m = 0; m < 8; m++) xs[lane + 64 * m] = x[t * EE + lane + 64 * m];
  __syncthreads();
  int l = lane >> 3, a = lane & 7;
  float r = 0.f;
  if (lane < 32) {
    r = xs[l * 128 + a];
#pragma unroll
    for (int m = 1; m < 16; m++) r = r + xs[l * 128 + 8 * m + a];
  }
  r = r + __shfl_xor(r, 1);
  r = r + __shfl_xor(r, 2);
  r = r + __shfl_xor(r, 4);
  r = r + __shfl_xor(r, 8);
  r = r + __shfl_xor(r, 16);
  if (lane == 0) bc[0] = r / 512.0f;
  __syncthreads();
  float mean = bc[0];
  r = 0.f;
  if (lane < 32) {
#pragma unroll
    for (int m = 0; m < 16; m++) {
      float d = sep(xs[l * 128 + 8 * m + a] - mean);
      float s2 = sep(d * d);
      r = (m == 0) ? s2 : (r + s2);
    }
  }
  r = r + __shfl_xor(r, 1);
  r = r + __shfl_xor(r, 2);
  r = r + __shfl_xor(r, 4);
  r = r + __shfl_xor(r, 8);
  r = r + __shfl_xor(r, 16);
  if (lane == 0) bc[1] = r / 512.0f;
  __syncthreads();
  float var = bc[1];
  float rs = 1.0f / sqrtf(var + 1e-5f);
#pragma unroll
  for (int m = 0; m < 8; m++) {
    int i = lane + 64 * m;
    float d = sep(xs[i] - mean);
    float t1 = sep(d * rs);
    float t2 = sep(t1 * g[i]);
    y[t * EE + i] = t2 + b[i];
  }
}

// ===== LayerNorm (LN2) with split bf16 hi/lo output (same frozen math, split store) =====
__global__ __launch_bounds__(64) void ln_np_s(const float* __restrict__ x,
                                              const float* __restrict__ g,
                                              const float* __restrict__ b,
                                              unsigned short* __restrict__ yh,
                                              unsigned short* __restrict__ yl) {
  __shared__ float xs[EE];
  __shared__ float bc[2];
  long long t = blockIdx.x;
  int lane = threadIdx.x;
#pragma unroll
  for (int m = 0; m < 8; m++) xs[lane + 64 * m] = x[t * EE + lane + 64 * m];
  __syncthreads();
  int l = lane >> 3, a = lane & 7;
  float r = 0.f;
  if (lane < 32) {
    r = xs[l * 128 + a];
#pragma unroll
    for (int m = 1; m < 16; m++) r = r + xs[l * 128 + 8 * m + a];
  }
  r = r + __shfl_xor(r, 1);
  r = r + __shfl_xor(r, 2);
  r = r + __shfl_xor(r, 4);
  r = r + __shfl_xor(r, 8);
  r = r + __shfl_xor(r, 16);
  if (lane == 0) bc[0] = r / 512.0f;
  __syncthreads();
  float mean = bc[0];
  r = 0.f;
  if (lane < 32) {
#pragma unroll
    for (int m = 0; m < 16; m++) {
      float d = sep(xs[l * 128 + 8 * m + a] - mean);
      float s2 = sep(d * d);
      r = (m == 0) ? s2 : (r + s2);
    }
  }
  r = r + __shfl_xor(r, 1);
  r = r + __shfl_xor(r, 2);
  r = r + __shfl_xor(r, 4);
  r = r + __shfl_xor(r, 8);
  r = r + __shfl_xor(r, 16);
  if (lane == 0) bc[1] = r / 512.0f;
  __syncthreads();
  float var = bc[1];
  float rs = 1.0f / sqrtf(var + 1e-5f);
#pragma unroll
  for (int m = 0; m < 8; m++) {
    int i = lane + 64 * m;
    float d = sep(xs[i] - mean);
    float t1 = sep(d * rs);
    float t2 = sep(t1 * g[i]);
    float o = t2 + b[i];
    unsigned short hh = f2bf(o);
    yh[t * EE + i] = hh;
    yl[t * EE + i] = f2bf(o - bf2f(hh));
  }
}

// ================= distances — FROZEN math; also emits E = __expf(dist) for ctx gate =================
__global__ __launch_bounds__(256) void dist_np(const float* __restrict__ nq,
                                               const float* __restrict__ conv_w,
                                               const float* __restrict__ conv_b,
                                               float* __restrict__ dist,
                                               float* __restrict__ Edist) {
  int bh = blockIdx.x;
  int b = bh >> 3, h = bh & 7;
  float cb = conv_b[h];
  const float* W = conv_w + (long long)h * EE * 3;
  int s = blockIdx.y * 256 + threadIdx.x;
  float d = cb;
#pragma unroll
  for (int k = 0; k < 3; k++) {
    int t = s - 2 + k;
    if (t < 0) continue;
    const float* row = nq + ((long long)b * SQ + t) * EE;
    float acc = 0.f;
    for (int e = 0; e < EE; e++) acc = __builtin_fmaf(row[e], W[e * 3 + k], acc);
    d = sep(d + acc);
  }
  float dv = (float)tanh((double)d);
  dist[(long long)bh * SQ + s] = dv;
  Edist[(long long)bh * SQ + s] = __expf(dv);  // d in [-1,1]: no overflow; numerator-only use
}

// ================= fp32 tiled NT-GEMM — FROZEN DAG (R12, byte-identical) =================
__device__ __forceinline__ float gelu_exact(float x) {
  return 0.5f * x * (1.f + erff(x / 1.41421356237309504880f));
}

template <int ACT, int SPLITK>
__global__ __launch_bounds__(256) void gemm_nt(const float* __restrict__ A, int lda, long long sA,
                                               const float* __restrict__ B, int ldb, long long sB,
                                               const float* __restrict__ bias,
                                               const float* __restrict__ Res,
                                               float* __restrict__ C, int ldc, long long sC,
                                               int K, float alpha) {
  __shared__ float As[16][68];
  __shared__ float Bs[16][68];
  int z = blockIdx.z;
  A += (long long)z * sA;
  B += (long long)z * sB;
  C += (long long)z * sC;
  int m0 = blockIdx.y * 64, n0 = blockIdx.x * 64;
  int tid = threadIdx.x;
  int lr = tid >> 2, lc = tid & 3;
  int tx = tid & 15, ty = tid >> 4;
  float acc[4][4] = {};
  float acc2[4][4] = {};
  const float* Arow = A + (long long)(m0 + lr) * lda + lc * 4;
  const float* Brow = B + (long long)(n0 + lr) * ldb + lc * 4;
  float4 a4 = *(const float4*)(Arow);
  float4 b4 = *(const float4*)(Brow);
  for (int k0 = 0; k0 < K; k0 += 16) {
    __syncthreads();
    As[lc * 4 + 0][lr] = a4.x; As[lc * 4 + 1][lr] = a4.y;
    As[lc * 4 + 2][lr] = a4.z; As[lc * 4 + 3][lr] = a4.w;
    Bs[lc * 4 + 0][lr] = b4.x; Bs[lc * 4 + 1][lr] = b4.y;
    Bs[lc * 4 + 2][lr] = b4.z; Bs[lc * 4 + 3][lr] = b4.w;
    __syncthreads();
    int kn = (k0 + 16 < K) ? (k0 + 16) : k0;
    float4 a4n = *(const float4*)(Arow + kn);
    float4 b4n = *(const float4*)(Brow + kn);
    float(*tgt)[4] = (SPLITK > 0 && k0 >= SPLITK) ? acc2 : acc;
#pragma unroll
    for (int kk = 0; kk < 16; kk++) {
      float4 av = *(const float4*)&As[kk][ty * 4];
      float4 bv = *(const float4*)&Bs[kk][tx * 4];
      float a[4] = {av.x, av.y, av.z, av.w};
      float bb[4] = {bv.x, bv.y, bv.z, bv.w};
#pragma unroll
      for (int i = 0; i < 4; i++)
#pragma unroll
        for (int j = 0; j < 4; j++) tgt[i][j] += a[i] * bb[j];
    }
    a4 = a4n;
    b4 = b4n;
  }
  if (SPLITK > 0) {
#pragma unroll
    for (int i = 0; i < 4; i++)
#pragma unroll
      for (int j = 0; j < 4; j++) acc[i][j] = sep(acc[i][j]) + acc2[i][j];
  }
  float4 bias4 = make_float4(0.f, 0.f, 0.f, 0.f);
  if (ACT != 2 && bias) bias4 = *(const float4*)(bias + n0 + tx * 4);
#pragma unroll
  for (int i = 0; i < 4; i++) {
    int row = m0 + ty * 4 + i;
    float o[4];
    if (ACT == 2) {
#pragma unroll
      for (int j = 0; j < 4; j++) o[j] = acc[i][j] / alpha;
    } else {
      o[0] = sep(acc[i][0] * alpha) + bias4.x;
      o[1] = sep(acc[i][1] * alpha) + bias4.y;
      o[2] = sep(acc[i][2] * alpha) + bias4.z;
      o[3] = sep(acc[i][3] * alpha) + bias4.w;
    }
    if (ACT == 1) {
#pragma unroll
      for (int j = 0; j < 4; j++) o[j] = gelu_exact(o[j]);
    }
    if (Res) {
      float4 r4 = *(const float4*)(Res + (long long)row * ldc + n0 + tx * 4);
      o[0] = sep(o[0]) + r4.x; o[1] = sep(o[1]) + r4.y;
      o[2] = sep(o[2]) + r4.z; o[3] = sep(o[3]) + r4.w;
    }
    *(float4*)(C + (long long)row * ldc + n0 + tx * 4) = make_float4(o[0], o[1], o[2], o[3]);
  }
}

// ================= gated row sums: np.sum pairwise(1024) — FROZEN (fp64 exp) =================
__global__ __launch_bounds__(64) void rowsum_np(const float* __restrict__ scores,
                                                const float* __restrict__ dist,
                                                float* __restrict__ invrs) {
  __shared__ float wsm[SQ];
  int i = blockIdx.x;
  int z = blockIdx.y;
  int b = z >> 3;
  const float* srow = scores + ((long long)b * SQ + i) * SQ;
  const float* dz = dist + (long long)z * SQ;
  float di = dz[i];
  int lane = threadIdx.x;
#pragma unroll
  for (int m = 0; m < 16; m++) {
    int j = lane + 64 * m;
    float e = (float)exp((double)(dz[j] - di));
    float gg = 1.f / (1.f + e);
    wsm[j] = srow[j] * gg;
  }
  __syncthreads();
  int l = lane >> 3, a = lane & 7;
  float r = wsm[l * 128 + a];
#pragma unroll
  for (int m = 1; m < 16; m++) r = r + wsm[l * 128 + 8 * m + a];
  r = r + __shfl_xor(r, 1);
  r = r + __shfl_xor(r, 2);
  r = r + __shfl_xor(r, 4);
  r = r + __shfl_xor(r, 8);
  r = r + __shfl_xor(r, 16);
  r = r + __shfl_xor(r, 32);
  if (lane == 0) invrs[(long long)z * SQ + i] = 1.f / (r + 1e-12f);
}

// ================= V transpose + bf16 hi/lo split:  VhT/VlT[b][e][j] = split(V[b][j][e]) =================
__global__ __launch_bounds__(256) void vsplit_t(const float* __restrict__ qkv,
                                                unsigned short* __restrict__ VhT,
                                                unsigned short* __restrict__ VlT) {
  __shared__ float tile[64][65];
  int b = blockIdx.z;
  int j0 = blockIdx.x * 64;  // S tile
  int e0 = blockIdx.y * 64;  // E tile
  const float* V = qkv + (long long)b * SQ * (3 * EE) + 2 * EE;
  unsigned short* Vh = VhT + (long long)b * EE * SQ;
  unsigned short* Vl = VlT + (long long)b * EE * SQ;
  int tx = threadIdx.x & 15, ty = threadIdx.x >> 4;
#pragma unroll
  for (int r = 0; r < 4; r++) {
    int j = j0 + ty + r * 16;
    float4 v = *(const float4*)(V + (long long)j * (3 * EE) + e0 + tx * 4);
    tile[ty + r * 16][tx * 4 + 0] = v.x;
    tile[ty + r * 16][tx * 4 + 1] = v.y;
    tile[ty + r * 16][tx * 4 + 2] = v.z;
    tile[ty + r * 16][tx * 4 + 3] = v.w;
  }
  __syncthreads();
#pragma unroll
  for (int r = 0; r < 4; r++) {
    int el = ty + r * 16;
    float4 f;
    f.x = tile[tx * 4 + 0][el];
    f.y = tile[tx * 4 + 1][el];
    f.z = tile[tx * 4 + 2][el];
    f.w = tile[tx * 4 + 3][el];
    u16x4 hh, ll;
    split4(f, hh, ll);
    long long o = (long long)(e0 + el) * SQ + j0 + tx * 4;
    *(u16x4*)(Vh + o) = hh;
    *(u16x4*)(Vl + o) = ll;
  }
}

// ===== flat fp32 -> bf16 hi/lo split (weights); n4 = count/4 =====
__global__ __launch_bounds__(256) void wsplit(const float* __restrict__ W,
                                              unsigned short* __restrict__ Wh,
                                              unsigned short* __restrict__ Wl, int n4) {
  int i = blockIdx.x * 256 + threadIdx.x;
  if (i >= n4) return;
  float4 v = *(const float4*)(W + (long long)i * 4);
  u16x4 h, l;
  split4(v, h, l);
  *(u16x4*)(Wh + (long long)i * 4) = h;
  *(u16x4*)(Wl + (long long)i * 4) = l;
}

// ================= ctx GEMM via bf16x3 MFMA — 128x256 tile, E-gate, cvt_pk split =================
// ctx[b,h,i,e] = sum_j (s[i,j] * Ei/(Ei+Ej) * inv_i) * V[j,e]
// NUMERATOR-ONLY approximations (proven-tolerant class): E-form gate with
// precomputed E (no exp in loop), cvt_pk bf16 hi/lo split. scores/invrs inputs
// are the frozen fp32 values. 4 waves, wave-tile 64x128 (96 MFMA/K-step),
// LDS 60 KiB -> 2 blocks/CU.
__global__ __launch_bounds__(256, 2) void ctx_bf3(const float* __restrict__ scores,
                                                  const float* __restrict__ Edist,
                                                  const float* __restrict__ invrs,
                                                  const unsigned short* __restrict__ VhT,
                                                  const unsigned short* __restrict__ VlT,
                                                  unsigned short* __restrict__ Ch,
                                                  unsigned short* __restrict__ Cl) {
  __shared__ __align__(16) unsigned short Ah[128 * 40], Al[128 * 40];
  __shared__ __align__(16) unsigned short Bh[256 * 40], Bl[256 * 40];
  int z = blockIdx.z, b = z >> 3, h = z & 7;
  const float* Sb = scores + (long long)b * SQ * SQ;
  const unsigned short* Vh = VhT + (long long)b * EE * SQ;
  const unsigned short* Vl = VlT + (long long)b * EE * SQ;
  unsigned short* Chb = Ch + (long long)b * SQ * (NH * EE) + h * EE;
  unsigned short* Clb = Cl + (long long)b * SQ * (NH * EE) + h * EE;
  const float* Ez = Edist + (long long)z * SQ;
  int m0 = blockIdx.y * 128, n0 = blockIdx.x * 256;
  int tid = threadIdx.x;
  int wave = tid >> 6, lane = tid & 63;
  int quad = lane >> 4, l16 = lane & 15;
  f32x4 acc[4][8];
#pragma unroll
  for (int mf = 0; mf < 4; mf++)
#pragma unroll
    for (int nf = 0; nf < 8; nf++) acc[mf][nf] = (f32x4)(0.f);

  // A staging: 2 threads/row, 16 elems each (4 float4 chunks kc = aakc*4+r)
  int aam = tid & 127, aakc = tid >> 7;
  float ei = Ez[m0 + aam];
  float inv = invrs[(long long)z * SQ + m0 + aam];
  float ci = ei * inv;
  const float* Srow = Sb + (long long)(m0 + aam) * SQ;
  // B staging: 1 thread/row, 4 u16x8 chunks per array
  int brow = tid;
  const unsigned short* VhRow = Vh + (long long)(n0 + brow) * SQ;
  const unsigned short* VlRow = Vl + (long long)(n0 + brow) * SQ;

  uint2 aHp[4], aLp[4];
  u16x8 bH[4], bL[4];

  auto loadconv = [&](int kb) {
#pragma unroll
    for (int r = 0; r < 4; r++) {
      int kc = aakc * 4 + r;
      float4 s4 = *(const float4*)(Srow + kb + kc * 4);
      float4 e4 = *(const float4*)(Ez + kb + kc * 4);
      float ax = (s4.x * ci) * __builtin_amdgcn_rcpf(ei + e4.x);
      float ay = (s4.y * ci) * __builtin_amdgcn_rcpf(ei + e4.y);
      float az = (s4.z * ci) * __builtin_amdgcn_rcpf(ei + e4.z);
      float aw = (s4.w * ci) * __builtin_amdgcn_rcpf(ei + e4.w);
      unsigned h01 = cvtpk(ax, ay), h23 = cvtpk(az, aw);
      float hx = bitf(h01 << 16), hy = bitf(h01 & 0xffff0000u);
      float hz = bitf(h23 << 16), hw = bitf(h23 & 0xffff0000u);
      unsigned l01 = cvtpk(ax - hx, ay - hy), l23 = cvtpk(az - hz, aw - hw);
      aHp[r] = make_uint2(h01, h23);
      aLp[r] = make_uint2(l01, l23);
    }
#pragma unroll
    for (int c = 0; c < 4; c++) {
      bH[c] = *(const u16x8*)(VhRow + kb + c * 8);
      bL[c] = *(const u16x8*)(VlRow + kb + c * 8);
    }
  };

  loadconv(0);
  for (int k0 = 0; k0 < SQ; k0 += 32) {
    __syncthreads();
#pragma unroll
    for (int r = 0; r < 4; r++) {
      *(uint2*)&Ah[swzi(aam, aakc * 4 + r)] = aHp[r];
      *(uint2*)&Al[swzi(aam, aakc * 4 + r)] = aLp[r];
    }
#pragma unroll
    for (int c = 0; c < 4; c++) {
      *(u16x8*)&Bh[swzi(brow, 2 * c)] = bH[c];
      *(u16x8*)&Bl[swzi(brow, 2 * c)] = bL[c];
    }
    __syncthreads();
    int kn = (k0 + 32 < SQ) ? (k0 + 32) : k0;  // clamped dummy reload
    loadconv(kn);
    bfrag ah[4], al_[4];
#pragma unroll
    for (int mf = 0; mf < 4; mf++) {
      int ra = (wave >> 1) * 64 + mf * 16 + l16;
      ah[mf] = *(const bfrag*)&Ah[swzi(ra, quad * 2)];
      al_[mf] = *(const bfrag*)&Al[swzi(ra, quad * 2)];
    }
#pragma unroll
    for (int nf = 0; nf < 8; nf++) {
      int rb = (wave & 1) * 128 + nf * 16 + l16;
      bfrag bh = *(const bfrag*)&Bh[swzi(rb, quad * 2)];
      bfrag bl = *(const bfrag*)&Bl[swzi(rb, quad * 2)];
#pragma unroll
      for (int mf = 0; mf < 4; mf++) {
        acc[mf][nf] = __builtin_amdgcn_mfma_f32_16x16x32_bf16(al_[mf], bh, acc[mf][nf], 0, 0, 0);
        acc[mf][nf] = __builtin_amdgcn_mfma_f32_16x16x32_bf16(ah[mf], bl, acc[mf][nf], 0, 0, 0);
        acc[mf][nf] = __builtin_amdgcn_mfma_f32_16x16x32_bf16(ah[mf], bh, acc[mf][nf], 0, 0, 0);
      }
    }
  }
#pragma unroll
  for (int mf = 0; mf < 4; mf++) {
#pragma unroll
    for (int nf = 0; nf < 8; nf++) {
      int col = n0 + (wave & 1) * 128 + nf * 16 + l16;
#pragma unroll
      for (int r = 0; r < 4; r++) {
        int row = m0 + (wave >> 1) * 64 + mf * 16 + quad * 4 + r;
        float o = acc[mf][nf][r];
        unsigned short hh = f2bf(o);
        Chb[(long long)row * (NH * EE) + col] = hh;
        Clb[(long long)row * (NH * EE) + col] = f2bf(o - bf2f(hh));
      }
    }
  }
}

// ================= bf16x3 MFMA NT-GEMM, pre-split operands, DMA-staged, WIDE =================
// 128x64 block, 4 waves x (64x32 sub-tile). Triple-buffered global_load_lds,
// prefetch distance 2, counted vmcnt(12). Source-side 2-bit chunk XOR swizzle.
// Per-output-element accumulation chain bit-identical to round-3/4 gemm_bf3s.
template <int ACT, int OUTM>
__global__ __launch_bounds__(256) void gemm_bf3w(
    const unsigned short* __restrict__ Ah_g, const unsigned short* __restrict__ Al_g, int lda,
    const unsigned short* __restrict__ Bh_g, const unsigned short* __restrict__ Bl_g, int ldb,
    const float* __restrict__ bias, const float* __restrict__ Res,
    float* __restrict__ C, unsigned short* __restrict__ Ch, unsigned short* __restrict__ Cl,
    int ldc, int K) {
  __shared__ __align__(16) unsigned short lds[3 * 12288];  // 3 bufs x 24 KB
  // XCD-aware block swizzle (nwg % 8 == 0 in all our launches)
  int gx = gridDim.x;
  int nwg = gx * (int)gridDim.y;
  int lin = blockIdx.y * gx + blockIdx.x;
  int cpx = nwg >> 3;
  int tl = (lin & 7) * cpx + (lin >> 3);
  int bx = tl % gx, by = tl / gx;
  int m0 = by * 128, n0 = bx * 64;
  int tid = threadIdx.x, wave = tid >> 6, lane = tid & 63;
  int quad = lane >> 4, l16 = lane & 15;

  // 24 DMA slots per K-tile (Ah:8, Al:8, Bh:4, Bl:4); wave w owns slots w*6..w*6+5
  const unsigned short* gptr[6];
  int ldsoff[6];
#pragma unroll
  for (int i = 0; i < 6; i++) {
    int d = wave * 6 + i;
    const unsigned short* src;
    int rowbase, ld, tb, qt;
    if (d < 8)       { src = Ah_g; rowbase = m0; ld = lda; tb = 0;     qt = d; }
    else if (d < 16) { src = Al_g; rowbase = m0; ld = lda; tb = 4096;  qt = d - 8; }
    else if (d < 20) { src = Bh_g; rowbase = n0; ld = ldb; tb = 8192;  qt = d - 16; }
    else             { src = Bl_g; rowbase = n0; ld = ldb; tb = 10240; qt = d - 20; }
    int row = qt * 16 + (lane >> 2);
    int cG = (lane & 3) ^ ((row >> 1) & 3);
    gptr[i] = src + (long long)(rowbase + row) * ld + cG * 8;
    ldsoff[i] = tb + qt * 512;
  }

  auto stage = [&](int buf, int kb) {
#pragma unroll
    for (int i = 0; i < 6; i++)
      __builtin_amdgcn_global_load_lds((glb_u32*)(gptr[i] + kb),
                                       (lds_u32*)&lds[buf * 12288 + ldsoff[i]], 16, 0, 0);
  };

  int aoff[4], boff[2];
#pragma unroll
  for (int mf = 0; mf < 4; mf++) {
    int r = (wave >> 1) * 64 + mf * 16 + l16;
    aoff[mf] = r * 32 + ((quad ^ ((r >> 1) & 3)) * 8);
  }
#pragma unroll
  for (int nf = 0; nf < 2; nf++) {
    int r = (wave & 1) * 32 + nf * 16 + l16;
    boff[nf] = r * 32 + ((quad ^ ((r >> 1) & 3)) * 8);
  }

  f32x4 acc[4][2];
#pragma unroll
  for (int mf = 0; mf < 4; mf++)
#pragma unroll
    for (int nf = 0; nf < 2; nf++) acc[mf][nf] = (f32x4)(0.f);

  int NT = K >> 5;
  stage(0, 0);
  stage(1, 32);
  int cur = 0;
  for (int t = 0; t < NT; t++) {
    int nb = cur + 2; if (nb >= 3) nb -= 3;
    int kf = (t + 2 < NT) ? (t + 2) * 32 : (NT - 1) * 32;  // tail: dummy (unread buffer)
    stage(nb, kf);
    asm volatile("s_waitcnt vmcnt(12)" ::: "memory");
    __builtin_amdgcn_s_barrier();
    __builtin_amdgcn_sched_barrier(0);
    const unsigned short* L = &lds[cur * 12288];
    bfrag bh[2], bl[2];
#pragma unroll
    for (int nf = 0; nf < 2; nf++) {
      bh[nf] = *(const bfrag*)&L[8192 + boff[nf]];
      bl[nf] = *(const bfrag*)&L[10240 + boff[nf]];
    }
#pragma unroll
    for (int mf = 0; mf < 4; mf++) {
      bfrag ah = *(const bfrag*)&L[aoff[mf]];
      bfrag al = *(const bfrag*)&L[4096 + aoff[mf]];
#pragma unroll
      for (int nf = 0; nf < 2; nf++) {
        acc[mf][nf] = __builtin_amdgcn_mfma_f32_16x16x32_bf16(al, bh[nf], acc[mf][nf], 0, 0, 0);
        acc[mf][nf] = __builtin_amdgcn_mfma_f32_16x16x32_bf16(ah, bl[nf], acc[mf][nf], 0, 0, 0);
        acc[mf][nf] = __builtin_amdgcn_mfma_f32_16x16x32_bf16(ah, bh[nf], acc[mf][nf], 0, 0, 0);
      }
    }
    __builtin_amdgcn_sched_barrier(0);
    __builtin_amdgcn_s_barrier();
    cur++; if (cur >= 3) cur -= 3;
  }

  // epilogue: C/D layout row = quad*4 + r, col = l16
#pragma unroll
  for (int mf = 0; mf < 4; mf++) {
#pragma unroll
    for (int nf = 0; nf < 2; nf++) {
      int col = n0 + (wave & 1) * 32 + nf * 16 + l16;
      float bi = bias ? bias[col] : 0.f;
#pragma unroll
      for (int r = 0; r < 4; r++) {
        int row = m0 + (wave >> 1) * 64 + mf * 16 + quad * 4 + r;
        float o = acc[mf][nf][r] + bi;
        if (ACT == 1) o = gelu_exact(o);
        if (OUTM == 0) {
          if (Res) o = o + Res[(long long)row * ldc + col];
          C[(long long)row * ldc + col] = o;
        } else {
          unsigned short hh = f2bf(o);
          Ch[(long long)row * ldc + col] = hh;
          Cl[(long long)row * ldc + col] = f2bf(o - bf2f(hh));
        }
      }
    }
  }
}

extern "C" void kernel_launch(void* const* d_in, const int* in_sizes, int n_in,
                              void* d_out, int out_size, void* d_ws, size_t ws_size,
                              hipStream_t stream) {
  const float* query     = (const float*)d_in[0];
  const float* ln1_g     = (const float*)d_in[1];
  const float* ln1_b     = (const float*)d_in[2];
  const float* in_proj_w = (const float*)d_in[3];
  const float* in_proj_b = (const float*)d_in[4];
  const float* out_w     = (const float*)d_in[5];
  const float* out_b     = (const float*)d_in[6];
  const float* conv_w    = (const float*)d_in[7];
  const float* conv_b    = (const float*)d_in[8];
  const float* ln2_g     = (const float*)d_in[9];
  const float* ln2_b     = (const float*)d_in[10];
  const float* mlp_w1    = (const float*)d_in[11];
  const float* mlp_b1    = (const float*)d_in[12];
  const float* mlp_w2    = (const float*)d_in[13];
  const float* mlp_b2    = (const float*)d_in[14];
  float* out = (float*)d_out;
  char* ws = (char*)d_ws;

  // Round-4 proven workspace layout (peak 112.25 MiB). Lifetime-disjoint reuse:
  float* nq     = (float*)(ws + 0);                      // [0,8)   dead after step 3
  float* qkv    = (float*)(ws + (8ull << 20));           // [8,32)  dead after step 4
  float* dist   = (float*)(ws + (32ull << 20));          // 128 KiB
  float* invrs  = (float*)(ws + (32ull << 20) + 131072); // 128 KiB
  float* scores = (float*)(ws + (32ull << 20) + 262144); // [32.25,48.25) dead after step 6
  unsigned short* VhT = (unsigned short*)(ws + 0);             // over dead nq, 4 MiB (3b-6)
  unsigned short* VlT = (unsigned short*)(ws + (4ull << 20));  // 4 MiB
  // ctx pre-split: [48.25,112.25)
  unsigned short* ctxh = (unsigned short*)(ws + (48ull << 20) + 262144);  // 32 MiB
  unsigned short* ctxl = (unsigned short*)(ws + (80ull << 20) + 262144);  // 32 MiB
  // weight splits in dead scores region (written 6b, live to 10):
  unsigned short* out_wh = (unsigned short*)(ws + (32ull << 20) + 262144);  // 4 MiB
  unsigned short* out_wl = out_wh + 2097152;                                // 4 MiB
  unsigned short* w1h    = out_wl + 2097152;                                // 2 MiB
  unsigned short* w1l    = w1h + 1048576;                                   // 2 MiB
  unsigned short* w2h    = w1l + 1048576;                                   // 2 MiB
  unsigned short* w2l    = w2h + 1048576;                                   // 2 MiB (ends at 48.25)
  // LN2 split over dead ctxh (after step 7):
  unsigned short* ln2h = (unsigned short*)(ws + (48ull << 20) + 262144);  // 4 MiB
  unsigned short* ln2l = ln2h + 2097152;                                  // 4 MiB
  // MLP hidden split over dead nq+qkv (after step 6):
  unsigned short* hbufh = (unsigned short*)(ws + 0);        // 16 MiB
  unsigned short* hbufl = hbufh + 8388608;                  // 16 MiB (ends at 32)
  // Edist (128 KiB) lives in d_out scratch: written step 2, read step 6;
  // step 7 (stream-ordered after 6) overwrites out with the real output.
  float* Edist = (float*)d_out;

  // 1. LN1 (frozen)
  ln_np<<<dim3(NB * SQ), 64, 0, stream>>>(query, ln1_g, ln1_b, nq);
  // 2. distances (frozen) + E = __expf(dist) for ctx gate
  dist_np<<<dim3(NB * NH, 4), 256, 0, stream>>>(nq, conv_w, conv_b, dist, Edist);
  // 3. qkv (frozen chain)  M=4096 N=1536 K=512
  gemm_nt<0, 384><<<dim3(24, 64, 1), 256, 0, stream>>>(nq, EE, 0, in_proj_w, EE, 0,
                                                       in_proj_b, nullptr, qkv, 3 * EE, 0, EE, 1.f);
  // 3b. V transpose + bf16 hi/lo split
  vsplit_t<<<dim3(16, 8, NB), 256, 0, stream>>>(qkv, VhT, VlT);
  // 4. scores (frozen chain + true division)  M=N=1024 K=512, batched B
  gemm_nt<2, 384><<<dim3(16, 16, NB), 256, 0, stream>>>(
      qkv, 3 * EE, (long long)SQ * 3 * EE, qkv + EE, 3 * EE, (long long)SQ * 3 * EE,
      nullptr, nullptr, scores, SQ, (long long)SQ * SQ, EE, sqrtf(512.0f));
  // 5. gated row sums (frozen, fp64 exp)
  rowsum_np<<<dim3(SQ, NB * NH), 64, 0, stream>>>(scores, dist, invrs);
  // 6. ctx via bf16x3 MFMA, 128x256 tile, E-gate  M=1024 N=512 K=1024, z = B*H
  ctx_bf3<<<dim3(2, 8, NB * NH), 256, 0, stream>>>(scores, Edist, invrs, VhT, VlT, ctxh, ctxl);
  // 6b. weight splits (scores region is dead now)
  wsplit<<<dim3(2048), 256, 0, stream>>>(out_w, out_wh, out_wl, 524288);
  wsplit<<<dim3(1024), 256, 0, stream>>>(mlp_w1, w1h, w1l, 262144);
  wsplit<<<dim3(1024), 256, 0, stream>>>(mlp_w2, w2h, w2l, 262144);
  // 7. attn_out + residual (wide DMA bf16x3)  M=4096 N=512 K=4096
  gemm_bf3w<0, 0><<<dim3(8, 32), 256, 0, stream>>>(ctxh, ctxl, NH * EE, out_wh, out_wl, NH * EE,
                                                   out_b, query, out, nullptr, nullptr,
                                                   EE, NH * EE);
  // 8. LN2, split output
  ln_np_s<<<dim3(NB * SQ), 64, 0, stream>>>(out, ln2_g, ln2_b, ln2h, ln2l);
  // 9. MLP1 + gelu, split output (wide DMA bf16x3)  M=4096 N=2048 K=512
  gemm_bf3w<1, 1><<<dim3(32, 32), 256, 0, stream>>>(ln2h, ln2l, EE, w1h, w1l, EE,
                                                    mlp_b1, nullptr, nullptr, hbufh, hbufl,
                                                    4 * EE, EE);
  // 10. MLP2 + residual (wide DMA bf16x3)  M=4096 N=512 K=2048
  gemm_bf3w<0, 0><<<dim3(8, 32), 256, 0, stream>>>(hbufh, hbufl, 4 * EE, w2h, w2l, 4 * EE,
                                                   mlp_b2, out, out, nullptr, nullptr,
                                                   EE, 4 * EE);
}